// Round 6
// baseline (415.076 us; speedup 1.0000x reference)
//
#include <hip/hip_runtime.h>
#include <utility>

#define NQ 6
#define DIM 64

namespace {

// ---- compile-time ring permutation (CNOT ladder), matching _ring_perm ----
constexpr int ring_entry(int r, int i) {
    int idx = i;
    for (int w = NQ - 1; w >= 0; --w) {
        int c = w;
        int t = (w + r) % NQ;
        int cbit = (idx >> (NQ - 1 - c)) & 1;
        idx ^= cbit << (NQ - 1 - t);
    }
    return idx;
}

// Logical->physical composed map after L rings (all rings are GF(2)-linear).
// Rings in order: R1 (after layer0), R2 (after layer1), R1 (after layer2).
constexpr int Mc(int L, int i) {
    if (L == 1) return ring_entry(1, i);
    if (L == 2) return ring_entry(1, ring_entry(2, i));
    if (L == 3) return ring_entry(1, ring_entry(2, ring_entry(1, i)));
    return i;
}

constexpr int Minv(int L, int p) {
    for (int i = 0; i < DIM; ++i) if (Mc(L, i) == p) return i;
    return -1;
}

} // namespace

// ---- 1-instr VALU quad lane swap: DPP quad_perm, lane -> lane ^ HS ----
template<int HS>
__device__ __forceinline__ float qswap(float v) {
    constexpr int ctl = (HS == 1) ? 0xB1          // [1,0,3,2]
                      : (HS == 2) ? 0x4E          // [2,3,0,1]
                                  : 0x1B;         // [3,2,1,0]
    return __int_as_float(__builtin_amdgcn_mov_dpp(__float_as_int(v), ctl, 0xF, 0xF, true));
}

// ===== gate application in the fixed physical frame via composed maps =====
// 4 lanes per row: lane sub = t&3 holds physical slots p = sub*16 + l, l in [0,16).
// p bit5 (=32) <-> sub bit1; p bit4 (=16) <-> sub bit0; p bits 3..0 <-> l.
// logical i = Minv(L, p) = Minv(L,l) ^ sub0*Minv(L,16) ^ sub1*Minv(L,32) (GF(2)-linear).

template<int LY, int W, int d, int... Ls>
__device__ __forceinline__ void wire_inlane(float* sr, float* si,
        float A0r, float A0i, float B0r, float B0i,
        float A1r, float A1i, float B1r, float B1i,
        std::integer_sequence<int, Ls...>) {
    (([&] {
        if constexpr (Ls < (Ls ^ d)) {
            constexpr int la = Ls, lb = Ls ^ d;
            constexpr int ra = (Minv(LY, la) >> (5 - W)) & 1;
            constexpr int rb = (Minv(LY, lb) >> (5 - W)) & 1;
            const float cAar = ra ? A1r : A0r, cAai = ra ? A1i : A0i;
            const float cBar = ra ? B1r : B0r, cBai = ra ? B1i : B0i;
            const float cAbr = rb ? A1r : A0r, cAbi = rb ? A1i : A0i;
            const float cBbr = rb ? B1r : B0r, cBbi = rb ? B1i : B0i;
            const float mar = sr[la], mai = si[la];
            const float mbr = sr[lb], mbi = si[lb];
            sr[la] = cAar*mar - cAai*mai + cBar*mbr - cBai*mbi;
            si[la] = cAar*mai + cAai*mar + cBar*mbi + cBai*mbr;
            sr[lb] = cAbr*mbr - cAbi*mbi + cBbr*mar - cBbi*mai;
            si[lb] = cAbr*mbi + cAbi*mbr + cBbr*mai + cBbi*mar;
        }
    }()), ...);
}

template<int LY, int W, int HS, int... Ls>
__device__ __forceinline__ void wire_cross0(float* sr, float* si,
        float A0r, float A0i, float B0r, float B0i,
        float A1r, float A1i, float B1r, float B1i,
        std::integer_sequence<int, Ls...>) {
    (([&] {
        constexpr int r = (Minv(LY, Ls) >> (5 - W)) & 1;
        const float cAr = r ? A1r : A0r, cAi = r ? A1i : A0i;
        const float cBr = r ? B1r : B0r, cBi = r ? B1i : B0i;
        const float mr = sr[Ls], mi = si[Ls];
        const float tr = qswap<HS>(mr), ti = qswap<HS>(mi);  // partner lane, same l
        sr[Ls] = cAr*mr - cAi*mi + cBr*tr - cBi*ti;
        si[Ls] = cAr*mi + cAi*mr + cBr*ti + cBi*tr;
    }()), ...);
}

template<int LY, int W, int HS, int d, int... Ls>
__device__ __forceinline__ void wire_crossd(float* sr, float* si,
        float A0r, float A0i, float B0r, float B0i,
        float A1r, float A1i, float B1r, float B1i,
        std::integer_sequence<int, Ls...>) {
    (([&] {
        if constexpr (Ls < (Ls ^ d)) {
            constexpr int la = Ls, lb = Ls ^ d;
            constexpr int ra = (Minv(LY, la) >> (5 - W)) & 1;
            constexpr int rb = (Minv(LY, lb) >> (5 - W)) & 1;
            const float cAar = ra ? A1r : A0r, cAai = ra ? A1i : A0i;
            const float cBar = ra ? B1r : B0r, cBai = ra ? B1i : B0i;
            const float cAbr = rb ? A1r : A0r, cAbi = rb ? A1i : A0i;
            const float cBbr = rb ? B1r : B0r, cBbi = rb ? B1i : B0i;
            const float mar = sr[la], mai = si[la];
            const float mbr = sr[lb], mbi = si[lb];
            const float tar = qswap<HS>(mbr), tai_ = qswap<HS>(mbi); // partner of (sub,la)
            const float tbr = qswap<HS>(mar), tbi_ = qswap<HS>(mai); // partner of (sub,lb)
            sr[la] = cAar*mar - cAai*mai + cBar*tar - cBai*tai_;
            si[la] = cAar*mai + cAai*mar + cBar*tai_ + cBai*tar;
            sr[lb] = cAbr*mbr - cAbi*mbi + cBbr*tbr - cBbi*tbi_;
            si[lb] = cAbr*mbi + cAbi*mbr + cBbr*tbi_ + cBbi*tbr;
        }
    }()), ...);
}

template<int LY, int W>
__device__ __forceinline__ void wire_apply(float* sr, float* si,
        const float* __restrict__ g, int sub) {
    constexpr int D  = Mc(LY, 1 << (5 - W));   // physical pair offset (linear map)
    constexpr int HS = (D >> 4) & 3;           // cross-lane XOR within the quad
    constexpr int d  = D & 15;                 // in-lane slot XOR
    constexpr int c32 = (Minv(LY, 32) >> (5 - W)) & 1;  // role flip from sub bit1
    constexpr int c16 = (Minv(LY, 16) >> (5 - W)) & 1;  // role flip from sub bit0

    // role-hoisted coefficients: slot role = r_l(l) ^ f(sub)
    float A0r, A0i, B0r, B0i, A1r, A1i, B1r, B1i;
    if constexpr (c32 == 0 && c16 == 0) {
        A0r = g[0]; A0i = g[1]; B0r = g[2]; B0i = g[3];
        A1r = g[6]; A1i = g[7]; B1r = g[4]; B1i = g[5];
    } else {
        const bool f = ((((sub >> 1) & c32) ^ (sub & c16)) & 1) != 0;
        A0r = f ? g[6] : g[0];  A0i = f ? g[7] : g[1];
        B0r = f ? g[4] : g[2];  B0i = f ? g[5] : g[3];
        A1r = f ? g[0] : g[6];  A1i = f ? g[1] : g[7];
        B1r = f ? g[2] : g[4];  B1i = f ? g[3] : g[5];
    }
    if constexpr (HS == 0) {
        wire_inlane<LY, W, d>(sr, si, A0r, A0i, B0r, B0i, A1r, A1i, B1r, B1i,
                              std::make_integer_sequence<int, 16>{});
    } else if constexpr (d == 0) {
        wire_cross0<LY, W, HS>(sr, si, A0r, A0i, B0r, B0i, A1r, A1i, B1r, B1i,
                               std::make_integer_sequence<int, 16>{});
    } else {
        wire_crossd<LY, W, HS, d>(sr, si, A0r, A0i, B0r, B0i, A1r, A1i, B1r, B1i,
                                  std::make_integer_sequence<int, 16>{});
    }
}

template<int LY>
__device__ __forceinline__ void layer_apply(float* sr, float* si,
        const float* __restrict__ g, int sub) {
    wire_apply<LY, 0>(sr, si, g,      sub);
    wire_apply<LY, 1>(sr, si, g + 8,  sub);
    wire_apply<LY, 2>(sr, si, g + 16, sub);
    wire_apply<LY, 3>(sr, si, g + 24, sub);
    wire_apply<LY, 4>(sr, si, g + 32, sub);
    wire_apply<LY, 5>(sr, si, g + 40, sub);
}

// ---- readout: fold M3 into constexpr signs (l part) + runtime sub flips ----
template<int... Ls>
__device__ __forceinline__ void readout_impl(const float* sr, const float* si, float* q,
                                             std::integer_sequence<int, Ls...>) {
    (([&] {
        constexpr int iv = Minv(3, Ls);
        const float pb = sr[Ls]*sr[Ls] + si[Ls]*si[Ls];
        q[0] += ((iv >> 5) & 1) ? -pb : pb;
        q[1] += ((iv >> 4) & 1) ? -pb : pb;
        q[2] += ((iv >> 3) & 1) ? -pb : pb;
        q[3] += ((iv >> 2) & 1) ? -pb : pb;
        q[4] += ((iv >> 1) & 1) ? -pb : pb;
        q[5] += ( iv       & 1) ? -pb : pb;
    }()), ...);
}

// ---- per-thread gate computation (fallback path only) ----
__device__ __forceinline__ void compute_gates6(const float* __restrict__ th, float* g) {
#pragma unroll
    for (int w = 0; w < NQ; ++w) {
        const float phi = th[w*3+0], theta = th[w*3+1], omega = th[w*3+2];
        float s, c, sa, ca, sb, cb;
        __sincosf(0.5f * theta, &s, &c);
        __sincosf(0.5f * (phi + omega), &sa, &ca);
        __sincosf(0.5f * (phi - omega), &sb, &cb);
        g[w*8+0] =  ca * c;  g[w*8+1] = -sa * c;
        g[w*8+2] = -cb * s;  g[w*8+3] = -sb * s;
        g[w*8+4] =  cb * s;  g[w*8+5] = -sb * s;
        g[w*8+6] =  ca * c;  g[w*8+7] =  sa * c;
    }
}

// ---- setup: gates (18x8) + Gt[j][m] = ln_g[j]*W2[m][j] (64x6) + C1/C2 ----
// ws floats: [0,144) gates, [144,528) Gt (j*6+m), [528,534) C1, [534,540) C2+b2
__global__ void setup_kernel(const float* __restrict__ th_s, const float* __restrict__ th_t,
                             const float* __restrict__ ln_g, const float* __restrict__ ln_b,
                             const float* __restrict__ W2, const float* __restrict__ b2,
                             float* __restrict__ ws) {
    const int t = threadIdx.x;
    if (t < 18) {
        const int l = t / 6, w = t % 6;
        const float* th = (l < 2) ? (th_s + (l * 6 + w) * 3) : (th_t + w * 3);
        const float phi = th[0], theta = th[1], omega = th[2];
        float s, c, sa, ca, sb, cb;
        sincosf(0.5f * theta, &s, &c);
        sincosf(0.5f * (phi + omega), &sa, &ca);
        sincosf(0.5f * (phi - omega), &sb, &cb);
        float* g = ws + t * 8;
        g[0] =  ca * c;  g[1] = -sa * c;
        g[2] = -cb * s;  g[3] = -sb * s;
        g[4] =  cb * s;  g[5] = -sb * s;
        g[6] =  ca * c;  g[7] =  sa * c;
    }
    if (t < 384) {
        const int j = t / 6, m = t % 6;
        ws[144 + t] = ln_g[j] * W2[m * 64 + j];
    }
    if (t < 6) {
        float c1 = 0.f, c2 = 0.f;
        for (int j = 0; j < 64; ++j) {
            c1 += ln_g[j] * W2[t * 64 + j];
            c2 += ln_b[j] * W2[t * 64 + j];
        }
        ws[528 + t] = c1;
        ws[534 + t] = c2 + b2[t];
    }
}

template<bool USE_WS>
__global__ __launch_bounds__(256, 8)   // 64-VGPR cap -> 8 blocks/CU (32 waves/CU)
void qmaml_kernel(
    const float* __restrict__ x,  const float* __restrict__ W1, const float* __restrict__ b1,
    const float* __restrict__ ln_g, const float* __restrict__ ln_b,
    const float* __restrict__ W2, const float* __restrict__ b2,
    const float* __restrict__ th_s, const float* __restrict__ th_t,
    const float* __restrict__ Wc, const float* __restrict__ bc,
    const float* __restrict__ ws, float* __restrict__ out, int nrows) {

    const int t   = blockIdx.x * 256 + threadIdx.x;
    const int row = t >> 2;
    const int sub = t & 3;             // (wire0,wire1) bits of my 16-amp block
    if (row >= nrows) return;

    // ---- load MY QUARTER of the x row (K-split across the quad) ----
    float4 xv[4];
    const float4* xp = (const float4*)(x + (long)row * 64 + sub * 16);
#pragma unroll
    for (int k = 0; k < 4; ++k) xv[k] = xp[k];

    // ---- fused matvec + relu + LN-stats + folded (g*W2) projection ----
    // Each lane computes a quarter dot; the quad reassembles with two DPP
    // butterflies. All 4 lanes end with bit-identical acc (commutativity),
    // so stats/A stay lockstep-consistent across the quad.
    float A[6]  = {0.f, 0.f, 0.f, 0.f, 0.f, 0.f};
    float C1[6] = {0.f, 0.f, 0.f, 0.f, 0.f, 0.f};
    float C2[6] = {0.f, 0.f, 0.f, 0.f, 0.f, 0.f};
    float s = 0.f, s2 = 0.f;

    const float4* wbase = (const float4*)(W1 + sub * 16);
    for (int j = 0; j < 64; ++j) {     // rolled; one iteration's W regs live at a time
        const float4* wr = wbase + j * 16;
        float p0 = 0.f, p1 = 0.f;
        {
            const float4 a4 = wr[0];
            const float4 b4 = wr[1];
            const float4 c4 = wr[2];
            const float4 d4 = wr[3];
            p0 = fmaf(a4.x, xv[0].x, p0); p0 = fmaf(a4.y, xv[0].y, p0);
            p0 = fmaf(a4.z, xv[0].z, p0); p0 = fmaf(a4.w, xv[0].w, p0);
            p1 = fmaf(b4.x, xv[1].x, p1); p1 = fmaf(b4.y, xv[1].y, p1);
            p1 = fmaf(b4.z, xv[1].z, p1); p1 = fmaf(b4.w, xv[1].w, p1);
            p0 = fmaf(c4.x, xv[2].x, p0); p0 = fmaf(c4.y, xv[2].y, p0);
            p0 = fmaf(c4.z, xv[2].z, p0); p0 = fmaf(c4.w, xv[2].w, p0);
            p1 = fmaf(d4.x, xv[3].x, p1); p1 = fmaf(d4.y, xv[3].y, p1);
            p1 = fmaf(d4.z, xv[3].z, p1); p1 = fmaf(d4.w, xv[3].w, p1);
        }
        float p = p0 + p1;
        p += qswap<1>(p);                       // pairwise
        p += qswap<2>(p);                       // full quad: all lanes = total
        const float acc = fmaxf(p + b1[j], 0.f);
        s += acc; s2 += acc * acc;
        if constexpr (USE_WS) {
            const float* Gt = ws + 144 + j * 6;
#pragma unroll
            for (int m = 0; m < 6; ++m) A[m] = fmaf(acc, Gt[m], A[m]);
        } else {
            const float gj = ln_g[j], bj = ln_b[j];
#pragma unroll
            for (int m = 0; m < 6; ++m) {
                const float w2 = W2[m * 64 + j];
                const float gw = gj * w2;
                A[m]  = fmaf(acc, gw, A[m]);
                C1[m] += gw;
                C2[m] = fmaf(bj, w2, C2[m]);
            }
        }
    }

    const float mu  = s  * (1.f / 64.f);
    const float var = s2 * (1.f / 64.f) - mu * mu;
    const float inv = rsqrtf(var + 1e-5f);

    // ---- z = tanh(...), per-wire (cos, sin) ----
    float vc[6], vsn[6];
#pragma unroll
    for (int m = 0; m < 6; ++m) {
        float c1v, c2v;
        if constexpr (USE_WS) { c1v = ws[528 + m]; c2v = ws[534 + m]; }
        else                  { c1v = C1[m];       c2v = C2[m] + b2[m]; }
        const float zp = inv * (A[m] - mu * c1v) + c2v;
        const float e  = __expf(2.f * zp);
        const float z  = 1.f - 2.f / (e + 1.f);
        const float half = 1.57079632679f * z;
        vsn[m] = __sinf(half);
        vc[m]  = __cosf(half);
    }

    float gf[48];
    const float* g0;
    if constexpr (USE_WS) g0 = ws;      // wave-uniform -> SGPR s_loads
    else { compute_gates6(th_s, gf); g0 = gf; }

    // ---- build my 16 amps IN PLACE; per-level folded coefs computed on
    // the fly from (SGPR) gates x vc/vsn -> no gar/gai/gbr/gbi arrays.
    // Backward in-place doubling: write k descending reads k>>1 <= k.
    float sr[16], si[16];
    {
        const int b0 = (sub >> 1) & 1, b1_ = sub & 1;
        // wire0 coefficient, role selected by sub bit1
        const float w0a = b0 ? g0[4] : g0[0];
        const float w0b = b0 ? g0[5] : g0[1];
        const float w0c = b0 ? g0[6] : g0[2];
        const float w0d = b0 ? g0[7] : g0[3];
        const float a0r = w0a * vc[0] + w0c * vsn[0];
        const float a0i = w0b * vc[0] + w0d * vsn[0];
        // wire1 coefficient, role selected by sub bit0
        const float w1a = b1_ ? g0[12] : g0[8];
        const float w1b = b1_ ? g0[13] : g0[9];
        const float w1c = b1_ ? g0[14] : g0[10];
        const float w1d = b1_ ? g0[15] : g0[11];
        const float a1r = w1a * vc[1] + w1c * vsn[1];
        const float a1i = w1b * vc[1] + w1d * vsn[1];
        const float c1r = a0r * a1r - a0i * a1i;
        const float c1i = a0r * a1i + a0i * a1r;
        // wire2 expansion (both roles)
        const float ga2r = g0[16] * vc[2] + g0[18] * vsn[2];
        const float ga2i = g0[17] * vc[2] + g0[19] * vsn[2];
        const float gb2r = g0[20] * vc[2] + g0[22] * vsn[2];
        const float gb2i = g0[21] * vc[2] + g0[23] * vsn[2];
        sr[0] = c1r * ga2r - c1i * ga2i;
        si[0] = c1r * ga2i + c1i * ga2r;
        sr[1] = c1r * gb2r - c1i * gb2i;
        si[1] = c1r * gb2i + c1i * gb2r;
    }
    {   // wire3: 2 -> 4
        const float gaR = g0[24] * vc[3] + g0[26] * vsn[3];
        const float gaI = g0[25] * vc[3] + g0[27] * vsn[3];
        const float gbR = g0[28] * vc[3] + g0[30] * vsn[3];
        const float gbI = g0[29] * vc[3] + g0[31] * vsn[3];
#pragma unroll
        for (int k = 3; k >= 0; --k) {
            const float yr = (k & 1) ? gbR : gaR;
            const float yi = (k & 1) ? gbI : gaI;
            const float hr = sr[k >> 1], hi = si[k >> 1];
            sr[k] = hr * yr - hi * yi;
            si[k] = hr * yi + hi * yr;
        }
    }
    {   // wire4: 4 -> 8
        const float gaR = g0[32] * vc[4] + g0[34] * vsn[4];
        const float gaI = g0[33] * vc[4] + g0[35] * vsn[4];
        const float gbR = g0[36] * vc[4] + g0[38] * vsn[4];
        const float gbI = g0[37] * vc[4] + g0[39] * vsn[4];
#pragma unroll
        for (int k = 7; k >= 0; --k) {
            const float yr = (k & 1) ? gbR : gaR;
            const float yi = (k & 1) ? gbI : gaI;
            const float hr = sr[k >> 1], hi = si[k >> 1];
            sr[k] = hr * yr - hi * yi;
            si[k] = hr * yi + hi * yr;
        }
    }
    {   // wire5: 8 -> 16
        const float gaR = g0[40] * vc[5] + g0[42] * vsn[5];
        const float gaI = g0[41] * vc[5] + g0[43] * vsn[5];
        const float gbR = g0[44] * vc[5] + g0[46] * vsn[5];
        const float gbI = g0[45] * vc[5] + g0[47] * vsn[5];
#pragma unroll
        for (int k = 15; k >= 0; --k) {
            const float yr = (k & 1) ? gbR : gaR;
            const float yi = (k & 1) ? gbI : gaI;
            const float hr = sr[k >> 1], hi = si[k >> 1];
            sr[k] = hr * yr - hi * yi;
            si[k] = hr * yi + hi * yr;
        }
    }

    // ---- layers act through composed maps; NO physical permutations ----
    if constexpr (USE_WS) {
        layer_apply<1>(sr, si, ws + 48, sub);
        layer_apply<2>(sr, si, ws + 96, sub);
    } else {
        compute_gates6(th_s + 18, gf);
        layer_apply<1>(sr, si, gf, sub);
        compute_gates6(th_t, gf);
        layer_apply<2>(sr, si, gf, sub);
    }

    // ---- <Z_w> readout through M3 ----
    float q[6] = {0.f, 0.f, 0.f, 0.f, 0.f, 0.f};
    readout_impl(sr, si, q, std::make_integer_sequence<int, 16>{});

    constexpr int K16 = Minv(3, 16);   // sub bit0 contribution to M3^-1
    constexpr int K32 = Minv(3, 32);   // sub bit1 contribution to M3^-1
    const int s0 = sub & 1, s1 = (sub >> 1) & 1;
#pragma unroll
    for (int w = 0; w < 6; ++w) {
        const int flip = (s0 & ((K16 >> (5 - w)) & 1)) ^ (s1 & ((K32 >> (5 - w)) & 1));
        float tq = flip ? -q[w] : q[w];
        tq += qswap<1>(tq);
        tq += qswap<2>(tq);            // all lanes hold the full quad sum
        q[w] = tq;
    }

    // ---- head: out = q @ Wc^T + bc (split store across the quad) ----
    float o[5];
#pragma unroll
    for (int n = 0; n < 5; ++n) {
        float v = bc[n];
#pragma unroll
        for (int w = 0; w < 6; ++w) v = fmaf(q[w], Wc[n * 6 + w], v);
        o[n] = v;
    }
    float* orow = out + (long)row * 5;
    if (sub == 3) { orow[3] = o[3]; orow[4] = o[4]; }
    else          { orow[sub] = o[sub]; }
}

extern "C" void kernel_launch(void* const* d_in, const int* in_sizes, int n_in,
                              void* d_out, int out_size, void* d_ws, size_t ws_size,
                              hipStream_t stream) {
    const float* x   = (const float*)d_in[0];
    const float* W1  = (const float*)d_in[1];
    const float* b1  = (const float*)d_in[2];
    const float* lng = (const float*)d_in[3];
    const float* lnb = (const float*)d_in[4];
    const float* W2  = (const float*)d_in[5];
    const float* b2  = (const float*)d_in[6];
    const float* ths = (const float*)d_in[7];
    const float* tht = (const float*)d_in[8];
    const float* Wc  = (const float*)d_in[9];
    const float* bc  = (const float*)d_in[10];
    float* out = (float*)d_out;
    float* ws  = (float*)d_ws;

    const int nrows = in_sizes[0] / 64;              // 131072
    const long nthreads = (long)nrows * 4;           // 4 lanes per row
    const int grid = (int)((nthreads + 255) / 256);

    if (ws_size >= 540 * sizeof(float)) {
        setup_kernel<<<1, 384, 0, stream>>>(ths, tht, lng, lnb, W2, b2, ws);
        qmaml_kernel<true><<<grid, 256, 0, stream>>>(x, W1, b1, lng, lnb, W2, b2,
                                                     ths, tht, Wc, bc, ws, out, nrows);
    } else {
        qmaml_kernel<false><<<grid, 256, 0, stream>>>(x, W1, b1, lng, lnb, W2, b2,
                                                      ths, tht, Wc, bc, nullptr, out, nrows);
    }
}

// Round 8
// 233.166 us; speedup vs baseline: 1.7802x; 1.7802x over previous
//
#include <hip/hip_runtime.h>
#include <utility>

#define NQ 6
#define DIM 64

namespace {

// ---- compile-time ring permutation (CNOT ladder), matching _ring_perm ----
constexpr int ring_entry(int r, int i) {
    int idx = i;
    for (int w = NQ - 1; w >= 0; --w) {
        int c = w;
        int t = (w + r) % NQ;
        int cbit = (idx >> (NQ - 1 - c)) & 1;
        idx ^= cbit << (NQ - 1 - t);
    }
    return idx;
}

// Logical->physical composed map after L rings (all rings are GF(2)-linear).
// Rings in order: R1 (after layer0), R2 (after layer1), R1 (after layer2).
constexpr int Mc(int L, int i) {
    if (L == 1) return ring_entry(1, i);
    if (L == 2) return ring_entry(1, ring_entry(2, i));
    if (L == 3) return ring_entry(1, ring_entry(2, ring_entry(1, i)));
    return i;
}

constexpr int Minv(int L, int p) {
    for (int i = 0; i < DIM; ++i) if (Mc(L, i) == p) return i;
    return -1;
}

} // namespace

// ---- 1-instr VALU quad lane swap: DPP quad_perm, lane -> lane ^ HS ----
template<int HS>
__device__ __forceinline__ float qswap(float v) {
    constexpr int ctl = (HS == 1) ? 0xB1          // [1,0,3,2]
                      : (HS == 2) ? 0x4E          // [2,3,0,1]
                                  : 0x1B;         // [3,2,1,0]
    return __int_as_float(__builtin_amdgcn_mov_dpp(__float_as_int(v), ctl, 0xF, 0xF, true));
}

// ===== gate application in the fixed physical frame via composed maps =====
// 4 lanes per row: lane sub = t&3 holds physical slots p = sub*16 + l, l in [0,16).
// p bit5 (=32) <-> sub bit1; p bit4 (=16) <-> sub bit0; p bits 3..0 <-> l.
// logical i = Minv(L, p) = Minv(L,l) ^ sub0*Minv(L,16) ^ sub1*Minv(L,32) (GF(2)-linear).

template<int LY, int W, int d, int... Ls>
__device__ __forceinline__ void wire_inlane(float* sr, float* si,
        float A0r, float A0i, float B0r, float B0i,
        float A1r, float A1i, float B1r, float B1i,
        std::integer_sequence<int, Ls...>) {
    (([&] {
        if constexpr (Ls < (Ls ^ d)) {
            constexpr int la = Ls, lb = Ls ^ d;
            constexpr int ra = (Minv(LY, la) >> (5 - W)) & 1;
            constexpr int rb = (Minv(LY, lb) >> (5 - W)) & 1;
            const float cAar = ra ? A1r : A0r, cAai = ra ? A1i : A0i;
            const float cBar = ra ? B1r : B0r, cBai = ra ? B1i : B0i;
            const float cAbr = rb ? A1r : A0r, cAbi = rb ? A1i : A0i;
            const float cBbr = rb ? B1r : B0r, cBbi = rb ? B1i : B0i;
            const float mar = sr[la], mai = si[la];
            const float mbr = sr[lb], mbi = si[lb];
            sr[la] = cAar*mar - cAai*mai + cBar*mbr - cBai*mbi;
            si[la] = cAar*mai + cAai*mar + cBar*mbi + cBai*mbr;
            sr[lb] = cAbr*mbr - cAbi*mbi + cBbr*mar - cBbi*mai;
            si[lb] = cAbr*mbi + cAbi*mbr + cBbr*mai + cBbi*mar;
        }
    }()), ...);
}

template<int LY, int W, int HS, int... Ls>
__device__ __forceinline__ void wire_cross0(float* sr, float* si,
        float A0r, float A0i, float B0r, float B0i,
        float A1r, float A1i, float B1r, float B1i,
        std::integer_sequence<int, Ls...>) {
    (([&] {
        constexpr int r = (Minv(LY, Ls) >> (5 - W)) & 1;
        const float cAr = r ? A1r : A0r, cAi = r ? A1i : A0i;
        const float cBr = r ? B1r : B0r, cBi = r ? B1i : B0i;
        const float mr = sr[Ls], mi = si[Ls];
        const float tr = qswap<HS>(mr), ti = qswap<HS>(mi);  // partner lane, same l
        sr[Ls] = cAr*mr - cAi*mi + cBr*tr - cBi*ti;
        si[Ls] = cAr*mi + cAi*mr + cBr*ti + cBi*tr;
    }()), ...);
}

template<int LY, int W, int HS, int d, int... Ls>
__device__ __forceinline__ void wire_crossd(float* sr, float* si,
        float A0r, float A0i, float B0r, float B0i,
        float A1r, float A1i, float B1r, float B1i,
        std::integer_sequence<int, Ls...>) {
    (([&] {
        if constexpr (Ls < (Ls ^ d)) {
            constexpr int la = Ls, lb = Ls ^ d;
            constexpr int ra = (Minv(LY, la) >> (5 - W)) & 1;
            constexpr int rb = (Minv(LY, lb) >> (5 - W)) & 1;
            const float cAar = ra ? A1r : A0r, cAai = ra ? A1i : A0i;
            const float cBar = ra ? B1r : B0r, cBai = ra ? B1i : B0i;
            const float cAbr = rb ? A1r : A0r, cAbi = rb ? A1i : A0i;
            const float cBbr = rb ? B1r : B0r, cBbi = rb ? B1i : B0i;
            const float mar = sr[la], mai = si[la];
            const float mbr = sr[lb], mbi = si[lb];
            const float tar = qswap<HS>(mbr), tai_ = qswap<HS>(mbi); // partner of (sub,la)
            const float tbr = qswap<HS>(mar), tbi_ = qswap<HS>(mai); // partner of (sub,lb)
            sr[la] = cAar*mar - cAai*mai + cBar*tar - cBai*tai_;
            si[la] = cAar*mai + cAai*mar + cBar*tai_ + cBai*tar;
            sr[lb] = cAbr*mbr - cAbi*mbi + cBbr*tbr - cBbi*tbi_;
            si[lb] = cAbr*mbi + cAbi*mbr + cBbr*tbi_ + cBbi*tbr;
        }
    }()), ...);
}

template<int LY, int W>
__device__ __forceinline__ void wire_apply(float* sr, float* si,
        const float* __restrict__ g, int sub) {
    constexpr int D  = Mc(LY, 1 << (5 - W));   // physical pair offset (linear map)
    constexpr int HS = (D >> 4) & 3;           // cross-lane XOR within the quad
    constexpr int d  = D & 15;                 // in-lane slot XOR
    constexpr int c32 = (Minv(LY, 32) >> (5 - W)) & 1;  // role flip from sub bit1
    constexpr int c16 = (Minv(LY, 16) >> (5 - W)) & 1;  // role flip from sub bit0

    // role-hoisted coefficients: slot role = r_l(l) ^ f(sub)
    float A0r, A0i, B0r, B0i, A1r, A1i, B1r, B1i;
    if constexpr (c32 == 0 && c16 == 0) {
        A0r = g[0]; A0i = g[1]; B0r = g[2]; B0i = g[3];
        A1r = g[6]; A1i = g[7]; B1r = g[4]; B1i = g[5];
    } else {
        const bool f = ((((sub >> 1) & c32) ^ (sub & c16)) & 1) != 0;
        A0r = f ? g[6] : g[0];  A0i = f ? g[7] : g[1];
        B0r = f ? g[4] : g[2];  B0i = f ? g[5] : g[3];
        A1r = f ? g[0] : g[6];  A1i = f ? g[1] : g[7];
        B1r = f ? g[2] : g[4];  B1i = f ? g[3] : g[5];
    }
    if constexpr (HS == 0) {
        wire_inlane<LY, W, d>(sr, si, A0r, A0i, B0r, B0i, A1r, A1i, B1r, B1i,
                              std::make_integer_sequence<int, 16>{});
    } else if constexpr (d == 0) {
        wire_cross0<LY, W, HS>(sr, si, A0r, A0i, B0r, B0i, A1r, A1i, B1r, B1i,
                               std::make_integer_sequence<int, 16>{});
    } else {
        wire_crossd<LY, W, HS, d>(sr, si, A0r, A0i, B0r, B0i, A1r, A1i, B1r, B1i,
                                  std::make_integer_sequence<int, 16>{});
    }
}

template<int LY>
__device__ __forceinline__ void layer_apply(float* sr, float* si,
        const float* __restrict__ g, int sub) {
    wire_apply<LY, 0>(sr, si, g,      sub);
    wire_apply<LY, 1>(sr, si, g + 8,  sub);
    wire_apply<LY, 2>(sr, si, g + 16, sub);
    wire_apply<LY, 3>(sr, si, g + 24, sub);
    wire_apply<LY, 4>(sr, si, g + 32, sub);
    wire_apply<LY, 5>(sr, si, g + 40, sub);
}

// ---- readout: fold M3 into constexpr signs (l part) + runtime sub flips ----
template<int... Ls>
__device__ __forceinline__ void readout_impl(const float* sr, const float* si, float* q,
                                             std::integer_sequence<int, Ls...>) {
    (([&] {
        constexpr int iv = Minv(3, Ls);
        const float pb = sr[Ls]*sr[Ls] + si[Ls]*si[Ls];
        q[0] += ((iv >> 5) & 1) ? -pb : pb;
        q[1] += ((iv >> 4) & 1) ? -pb : pb;
        q[2] += ((iv >> 3) & 1) ? -pb : pb;
        q[3] += ((iv >> 2) & 1) ? -pb : pb;
        q[4] += ((iv >> 1) & 1) ? -pb : pb;
        q[5] += ( iv       & 1) ? -pb : pb;
    }()), ...);
}

// ---- per-thread gate computation (fallback path only) ----
__device__ __forceinline__ void compute_gates6(const float* __restrict__ th, float* g) {
#pragma unroll
    for (int w = 0; w < NQ; ++w) {
        const float phi = th[w*3+0], theta = th[w*3+1], omega = th[w*3+2];
        float s, c, sa, ca, sb, cb;
        __sincosf(0.5f * theta, &s, &c);
        __sincosf(0.5f * (phi + omega), &sa, &ca);
        __sincosf(0.5f * (phi - omega), &sb, &cb);
        g[w*8+0] =  ca * c;  g[w*8+1] = -sa * c;
        g[w*8+2] = -cb * s;  g[w*8+3] = -sb * s;
        g[w*8+4] =  cb * s;  g[w*8+5] = -sb * s;
        g[w*8+6] =  ca * c;  g[w*8+7] =  sa * c;
    }
}

// ---- setup: gates (18x8) + Gt[j][m] = ln_g[j]*W2[m][j] (64x6) + C1/C2 ----
// ws floats: [0,144) gates, [144,528) Gt (j*6+m), [528,534) C1, [534,540) C2+b2
__global__ void setup_kernel(const float* __restrict__ th_s, const float* __restrict__ th_t,
                             const float* __restrict__ ln_g, const float* __restrict__ ln_b,
                             const float* __restrict__ W2, const float* __restrict__ b2,
                             float* __restrict__ ws) {
    const int t = threadIdx.x;
    if (t < 18) {
        const int l = t / 6, w = t % 6;
        const float* th = (l < 2) ? (th_s + (l * 6 + w) * 3) : (th_t + w * 3);
        const float phi = th[0], theta = th[1], omega = th[2];
        float s, c, sa, ca, sb, cb;
        sincosf(0.5f * theta, &s, &c);
        sincosf(0.5f * (phi + omega), &sa, &ca);
        sincosf(0.5f * (phi - omega), &sb, &cb);
        float* g = ws + t * 8;
        g[0] =  ca * c;  g[1] = -sa * c;
        g[2] = -cb * s;  g[3] = -sb * s;
        g[4] =  cb * s;  g[5] = -sb * s;
        g[6] =  ca * c;  g[7] =  sa * c;
    }
    if (t < 384) {
        const int j = t / 6, m = t % 6;
        ws[144 + t] = ln_g[j] * W2[m * 64 + j];
    }
    if (t < 6) {
        float c1 = 0.f, c2 = 0.f;
        for (int j = 0; j < 64; ++j) {
            c1 += ln_g[j] * W2[t * 64 + j];
            c2 += ln_b[j] * W2[t * 64 + j];
        }
        ws[528 + t] = c1;
        ws[534 + t] = c2 + b2[t];
    }
}

template<bool USE_WS>
__global__ __launch_bounds__(256, 4)   // 128-VGPR budget: let allocator FIT (~90), no spill
void qmaml_kernel(
    const float* __restrict__ x,  const float* __restrict__ W1, const float* __restrict__ b1,
    const float* __restrict__ ln_g, const float* __restrict__ ln_b,
    const float* __restrict__ W2, const float* __restrict__ b2,
    const float* __restrict__ th_s, const float* __restrict__ th_t,
    const float* __restrict__ Wc, const float* __restrict__ bc,
    const float* __restrict__ ws, float* __restrict__ out, int nrows) {

    const int t   = blockIdx.x * 256 + threadIdx.x;
    const int row = t >> 2;
    const int sub = t & 3;             // (wire0,wire1) bits of my 16-amp block
    if (row >= nrows) return;

    // ---- load MY QUARTER of the x row (K-split across the quad) ----
    float4 xv[4];
    const float4* xp = (const float4*)(x + (long)row * 64 + sub * 16);
#pragma unroll
    for (int k = 0; k < 4; ++k) xv[k] = xp[k];

    // ---- fused matvec + relu + LN-stats + folded (g*W2) projection ----
    // Each lane computes a quarter dot; the quad reassembles with two DPP
    // butterflies. All 4 lanes end with bit-identical acc (commutativity),
    // so stats/A stay lockstep-consistent across the quad.
    float A[6]  = {0.f, 0.f, 0.f, 0.f, 0.f, 0.f};
    float C1[6] = {0.f, 0.f, 0.f, 0.f, 0.f, 0.f};
    float C2[6] = {0.f, 0.f, 0.f, 0.f, 0.f, 0.f};
    float s = 0.f, s2 = 0.f;

    const float4* wbase = (const float4*)(W1 + sub * 16);
    for (int j = 0; j < 64; ++j) {     // rolled; one iteration's W regs live at a time
        const float4* wr = wbase + j * 16;
        float p0 = 0.f, p1 = 0.f;
        {
            const float4 a4 = wr[0];
            const float4 b4 = wr[1];
            const float4 c4 = wr[2];
            const float4 d4 = wr[3];
            p0 = fmaf(a4.x, xv[0].x, p0); p0 = fmaf(a4.y, xv[0].y, p0);
            p0 = fmaf(a4.z, xv[0].z, p0); p0 = fmaf(a4.w, xv[0].w, p0);
            p1 = fmaf(b4.x, xv[1].x, p1); p1 = fmaf(b4.y, xv[1].y, p1);
            p1 = fmaf(b4.z, xv[1].z, p1); p1 = fmaf(b4.w, xv[1].w, p1);
            p0 = fmaf(c4.x, xv[2].x, p0); p0 = fmaf(c4.y, xv[2].y, p0);
            p0 = fmaf(c4.z, xv[2].z, p0); p0 = fmaf(c4.w, xv[2].w, p0);
            p1 = fmaf(d4.x, xv[3].x, p1); p1 = fmaf(d4.y, xv[3].y, p1);
            p1 = fmaf(d4.z, xv[3].z, p1); p1 = fmaf(d4.w, xv[3].w, p1);
        }
        float p = p0 + p1;
        p += qswap<1>(p);                       // pairwise
        p += qswap<2>(p);                       // full quad: all lanes = total
        const float acc = fmaxf(p + b1[j], 0.f);
        s += acc; s2 += acc * acc;
        if constexpr (USE_WS) {
            const float* Gt = ws + 144 + j * 6;
#pragma unroll
            for (int m = 0; m < 6; ++m) A[m] = fmaf(acc, Gt[m], A[m]);
        } else {
            const float gj = ln_g[j], bj = ln_b[j];
#pragma unroll
            for (int m = 0; m < 6; ++m) {
                const float w2 = W2[m * 64 + j];
                const float gw = gj * w2;
                A[m]  = fmaf(acc, gw, A[m]);
                C1[m] += gw;
                C2[m] = fmaf(bj, w2, C2[m]);
            }
        }
    }

    const float mu  = s  * (1.f / 64.f);
    const float var = s2 * (1.f / 64.f) - mu * mu;
    const float inv = rsqrtf(var + 1e-5f);

    // ---- z = tanh(...), per-wire (cos, sin) ----
    float vc[6], vsn[6];
#pragma unroll
    for (int m = 0; m < 6; ++m) {
        float c1v, c2v;
        if constexpr (USE_WS) { c1v = ws[528 + m]; c2v = ws[534 + m]; }
        else                  { c1v = C1[m];       c2v = C2[m] + b2[m]; }
        const float zp = inv * (A[m] - mu * c1v) + c2v;
        const float e  = __expf(2.f * zp);
        const float z  = 1.f - 2.f / (e + 1.f);
        const float half = 1.57079632679f * z;
        vsn[m] = __sinf(half);
        vc[m]  = __cosf(half);
    }

    float gf[48];
    const float* g0;
    if constexpr (USE_WS) g0 = ws;      // wave-uniform -> SGPR s_loads
    else { compute_gates6(th_s, gf); g0 = gf; }

    // ---- build my 16 amps IN PLACE; per-level folded coefs computed on
    // the fly from (SGPR) gates x vc/vsn -> no gar/gai/gbr/gbi arrays.
    // Backward in-place doubling: write k descending reads k>>1 <= k.
    float sr[16], si[16];
    {
        const int b0 = (sub >> 1) & 1, b1_ = sub & 1;
        // wire0 coefficient, role selected by sub bit1
        const float w0a = b0 ? g0[4] : g0[0];
        const float w0b = b0 ? g0[5] : g0[1];
        const float w0c = b0 ? g0[6] : g0[2];
        const float w0d = b0 ? g0[7] : g0[3];
        const float a0r = w0a * vc[0] + w0c * vsn[0];
        const float a0i = w0b * vc[0] + w0d * vsn[0];
        // wire1 coefficient, role selected by sub bit0
        const float w1a = b1_ ? g0[12] : g0[8];
        const float w1b = b1_ ? g0[13] : g0[9];
        const float w1c = b1_ ? g0[14] : g0[10];
        const float w1d = b1_ ? g0[15] : g0[11];
        const float a1r = w1a * vc[1] + w1c * vsn[1];
        const float a1i = w1b * vc[1] + w1d * vsn[1];
        const float c1r = a0r * a1r - a0i * a1i;
        const float c1i = a0r * a1i + a0i * a1r;
        // wire2 expansion (both roles)
        const float ga2r = g0[16] * vc[2] + g0[18] * vsn[2];
        const float ga2i = g0[17] * vc[2] + g0[19] * vsn[2];
        const float gb2r = g0[20] * vc[2] + g0[22] * vsn[2];
        const float gb2i = g0[21] * vc[2] + g0[23] * vsn[2];
        sr[0] = c1r * ga2r - c1i * ga2i;
        si[0] = c1r * ga2i + c1i * ga2r;
        sr[1] = c1r * gb2r - c1i * gb2i;
        si[1] = c1r * gb2i + c1i * gb2r;
    }
    {   // wire3: 2 -> 4
        const float gaR = g0[24] * vc[3] + g0[26] * vsn[3];
        const float gaI = g0[25] * vc[3] + g0[27] * vsn[3];
        const float gbR = g0[28] * vc[3] + g0[30] * vsn[3];
        const float gbI = g0[29] * vc[3] + g0[31] * vsn[3];
#pragma unroll
        for (int k = 3; k >= 0; --k) {
            const float yr = (k & 1) ? gbR : gaR;
            const float yi = (k & 1) ? gbI : gaI;
            const float hr = sr[k >> 1], hi = si[k >> 1];
            sr[k] = hr * yr - hi * yi;
            si[k] = hr * yi + hi * yr;
        }
    }
    {   // wire4: 4 -> 8
        const float gaR = g0[32] * vc[4] + g0[34] * vsn[4];
        const float gaI = g0[33] * vc[4] + g0[35] * vsn[4];
        const float gbR = g0[36] * vc[4] + g0[38] * vsn[4];
        const float gbI = g0[37] * vc[4] + g0[39] * vsn[4];
#pragma unroll
        for (int k = 7; k >= 0; --k) {
            const float yr = (k & 1) ? gbR : gaR;
            const float yi = (k & 1) ? gbI : gaI;
            const float hr = sr[k >> 1], hi = si[k >> 1];
            sr[k] = hr * yr - hi * yi;
            si[k] = hr * yi + hi * yr;
        }
    }
    {   // wire5: 8 -> 16
        const float gaR = g0[40] * vc[5] + g0[42] * vsn[5];
        const float gaI = g0[41] * vc[5] + g0[43] * vsn[5];
        const float gbR = g0[44] * vc[5] + g0[46] * vsn[5];
        const float gbI = g0[45] * vc[5] + g0[47] * vsn[5];
#pragma unroll
        for (int k = 15; k >= 0; --k) {
            const float yr = (k & 1) ? gbR : gaR;
            const float yi = (k & 1) ? gbI : gaI;
            const float hr = sr[k >> 1], hi = si[k >> 1];
            sr[k] = hr * yr - hi * yi;
            si[k] = hr * yi + hi * yr;
        }
    }

    // ---- layers act through composed maps; NO physical permutations ----
    if constexpr (USE_WS) {
        layer_apply<1>(sr, si, ws + 48, sub);
        layer_apply<2>(sr, si, ws + 96, sub);
    } else {
        compute_gates6(th_s + 18, gf);
        layer_apply<1>(sr, si, gf, sub);
        compute_gates6(th_t, gf);
        layer_apply<2>(sr, si, gf, sub);
    }

    // ---- <Z_w> readout through M3 ----
    float q[6] = {0.f, 0.f, 0.f, 0.f, 0.f, 0.f};
    readout_impl(sr, si, q, std::make_integer_sequence<int, 16>{});

    constexpr int K16 = Minv(3, 16);   // sub bit0 contribution to M3^-1
    constexpr int K32 = Minv(3, 32);   // sub bit1 contribution to M3^-1
    const int s0 = sub & 1, s1 = (sub >> 1) & 1;
#pragma unroll
    for (int w = 0; w < 6; ++w) {
        const int flip = (s0 & ((K16 >> (5 - w)) & 1)) ^ (s1 & ((K32 >> (5 - w)) & 1));
        float tq = flip ? -q[w] : q[w];
        tq += qswap<1>(tq);
        tq += qswap<2>(tq);            // all lanes hold the full quad sum
        q[w] = tq;
    }

    // ---- head: out = q @ Wc^T + bc (split store across the quad) ----
    float o[5];
#pragma unroll
    for (int n = 0; n < 5; ++n) {
        float v = bc[n];
#pragma unroll
        for (int w = 0; w < 6; ++w) v = fmaf(q[w], Wc[n * 6 + w], v);
        o[n] = v;
    }
    float* orow = out + (long)row * 5;
    if (sub == 3) { orow[3] = o[3]; orow[4] = o[4]; }
    else          { orow[sub] = o[sub]; }
}

extern "C" void kernel_launch(void* const* d_in, const int* in_sizes, int n_in,
                              void* d_out, int out_size, void* d_ws, size_t ws_size,
                              hipStream_t stream) {
    const float* x   = (const float*)d_in[0];
    const float* W1  = (const float*)d_in[1];
    const float* b1  = (const float*)d_in[2];
    const float* lng = (const float*)d_in[3];
    const float* lnb = (const float*)d_in[4];
    const float* W2  = (const float*)d_in[5];
    const float* b2  = (const float*)d_in[6];
    const float* ths = (const float*)d_in[7];
    const float* tht = (const float*)d_in[8];
    const float* Wc  = (const float*)d_in[9];
    const float* bc  = (const float*)d_in[10];
    float* out = (float*)d_out;
    float* ws  = (float*)d_ws;

    const int nrows = in_sizes[0] / 64;              // 131072
    const long nthreads = (long)nrows * 4;           // 4 lanes per row
    const int grid = (int)((nthreads + 255) / 256);

    if (ws_size >= 540 * sizeof(float)) {
        setup_kernel<<<1, 384, 0, stream>>>(ths, tht, lng, lnb, W2, b2, ws);
        qmaml_kernel<true><<<grid, 256, 0, stream>>>(x, W1, b1, lng, lnb, W2, b2,
                                                     ths, tht, Wc, bc, ws, out, nrows);
    } else {
        qmaml_kernel<false><<<grid, 256, 0, stream>>>(x, W1, b1, lng, lnb, W2, b2,
                                                      ths, tht, Wc, bc, nullptr, out, nrows);
    }
}

// Round 9
// 158.967 us; speedup vs baseline: 2.6111x; 1.4668x over previous
//
#include <hip/hip_runtime.h>
#include <utility>

#define NQ 6
#define DIM 64

namespace {

// ---- compile-time ring permutation (CNOT ladder), matching _ring_perm ----
constexpr int ring_entry(int r, int i) {
    int idx = i;
    for (int w = NQ - 1; w >= 0; --w) {
        int c = w;
        int t = (w + r) % NQ;
        int cbit = (idx >> (NQ - 1 - c)) & 1;
        idx ^= cbit << (NQ - 1 - t);
    }
    return idx;
}

// Logical->physical composed map after L rings (all rings are GF(2)-linear).
// Rings in order: R1 (after layer0), R2 (after layer1), R1 (after layer2).
constexpr int Mc(int L, int i) {
    if (L == 1) return ring_entry(1, i);
    if (L == 2) return ring_entry(1, ring_entry(2, i));
    if (L == 3) return ring_entry(1, ring_entry(2, ring_entry(1, i)));
    return i;
}

constexpr int Minv(int L, int p) {
    for (int i = 0; i < DIM; ++i) if (Mc(L, i) == p) return i;
    return -1;
}

} // namespace

// ---- 1-instr VALU quad lane swap: DPP quad_perm, lane -> lane ^ HS ----
template<int HS>
__device__ __forceinline__ float qswap(float v) {
    constexpr int ctl = (HS == 1) ? 0xB1          // [1,0,3,2]
                      : (HS == 2) ? 0x4E          // [2,3,0,1]
                                  : 0x1B;         // [3,2,1,0]
    return __int_as_float(__builtin_amdgcn_mov_dpp(__float_as_int(v), ctl, 0xF, 0xF, true));
}

// ===== gate application in the fixed physical frame via composed maps =====
// 4 lanes per row: lane sub = t&3 holds physical slots p = sub*16 + l, l in [0,16).
// p bit5 (=32) <-> sub bit1; p bit4 (=16) <-> sub bit0; p bits 3..0 <-> l.
// logical i = Minv(L, p) = Minv(L,l) ^ sub0*Minv(L,16) ^ sub1*Minv(L,32) (GF(2)-linear).

template<int LY, int W, int d, int... Ls>
__device__ __forceinline__ void wire_inlane(float* sr, float* si,
        float A0r, float A0i, float B0r, float B0i,
        float A1r, float A1i, float B1r, float B1i,
        std::integer_sequence<int, Ls...>) {
    (([&] {
        if constexpr (Ls < (Ls ^ d)) {
            constexpr int la = Ls, lb = Ls ^ d;
            constexpr int ra = (Minv(LY, la) >> (5 - W)) & 1;
            constexpr int rb = (Minv(LY, lb) >> (5 - W)) & 1;
            const float cAar = ra ? A1r : A0r, cAai = ra ? A1i : A0i;
            const float cBar = ra ? B1r : B0r, cBai = ra ? B1i : B0i;
            const float cAbr = rb ? A1r : A0r, cAbi = rb ? A1i : A0i;
            const float cBbr = rb ? B1r : B0r, cBbi = rb ? B1i : B0i;
            const float mar = sr[la], mai = si[la];
            const float mbr = sr[lb], mbi = si[lb];
            sr[la] = cAar*mar - cAai*mai + cBar*mbr - cBai*mbi;
            si[la] = cAar*mai + cAai*mar + cBar*mbi + cBai*mbr;
            sr[lb] = cAbr*mbr - cAbi*mbi + cBbr*mar - cBbi*mai;
            si[lb] = cAbr*mbi + cAbi*mbr + cBbr*mai + cBbi*mar;
        }
    }()), ...);
}

template<int LY, int W, int HS, int... Ls>
__device__ __forceinline__ void wire_cross0(float* sr, float* si,
        float A0r, float A0i, float B0r, float B0i,
        float A1r, float A1i, float B1r, float B1i,
        std::integer_sequence<int, Ls...>) {
    (([&] {
        constexpr int r = (Minv(LY, Ls) >> (5 - W)) & 1;
        const float cAr = r ? A1r : A0r, cAi = r ? A1i : A0i;
        const float cBr = r ? B1r : B0r, cBi = r ? B1i : B0i;
        const float mr = sr[Ls], mi = si[Ls];
        const float tr = qswap<HS>(mr), ti = qswap<HS>(mi);  // partner lane, same l
        sr[Ls] = cAr*mr - cAi*mi + cBr*tr - cBi*ti;
        si[Ls] = cAr*mi + cAi*mr + cBr*ti + cBi*tr;
    }()), ...);
}

template<int LY, int W, int HS, int d, int... Ls>
__device__ __forceinline__ void wire_crossd(float* sr, float* si,
        float A0r, float A0i, float B0r, float B0i,
        float A1r, float A1i, float B1r, float B1i,
        std::integer_sequence<int, Ls...>) {
    (([&] {
        if constexpr (Ls < (Ls ^ d)) {
            constexpr int la = Ls, lb = Ls ^ d;
            constexpr int ra = (Minv(LY, la) >> (5 - W)) & 1;
            constexpr int rb = (Minv(LY, lb) >> (5 - W)) & 1;
            const float cAar = ra ? A1r : A0r, cAai = ra ? A1i : A0i;
            const float cBar = ra ? B1r : B0r, cBai = ra ? B1i : B0i;
            const float cAbr = rb ? A1r : A0r, cAbi = rb ? A1i : A0i;
            const float cBbr = rb ? B1r : B0r, cBbi = rb ? B1i : B0i;
            const float mar = sr[la], mai = si[la];
            const float mbr = sr[lb], mbi = si[lb];
            const float tar = qswap<HS>(mbr), tai_ = qswap<HS>(mbi); // partner of (sub,la)
            const float tbr = qswap<HS>(mar), tbi_ = qswap<HS>(mai); // partner of (sub,lb)
            sr[la] = cAar*mar - cAai*mai + cBar*tar - cBai*tai_;
            si[la] = cAar*mai + cAai*mar + cBar*tai_ + cBai*tar;
            sr[lb] = cAbr*mbr - cAbi*mbi + cBbr*tbr - cBbi*tbi_;
            si[lb] = cAbr*mbi + cAbi*mbr + cBbr*tbi_ + cBbi*tbr;
        }
    }()), ...);
}

template<int LY, int W>
__device__ __forceinline__ void wire_apply(float* sr, float* si,
        const float* __restrict__ g, int sub) {
    constexpr int D  = Mc(LY, 1 << (5 - W));   // physical pair offset (linear map)
    constexpr int HS = (D >> 4) & 3;           // cross-lane XOR within the quad
    constexpr int d  = D & 15;                 // in-lane slot XOR
    constexpr int c32 = (Minv(LY, 32) >> (5 - W)) & 1;  // role flip from sub bit1
    constexpr int c16 = (Minv(LY, 16) >> (5 - W)) & 1;  // role flip from sub bit0

    // role-hoisted coefficients: slot role = r_l(l) ^ f(sub)
    float A0r, A0i, B0r, B0i, A1r, A1i, B1r, B1i;
    if constexpr (c32 == 0 && c16 == 0) {
        A0r = g[0]; A0i = g[1]; B0r = g[2]; B0i = g[3];
        A1r = g[6]; A1i = g[7]; B1r = g[4]; B1i = g[5];
    } else {
        const bool f = ((((sub >> 1) & c32) ^ (sub & c16)) & 1) != 0;
        A0r = f ? g[6] : g[0];  A0i = f ? g[7] : g[1];
        B0r = f ? g[4] : g[2];  B0i = f ? g[5] : g[3];
        A1r = f ? g[0] : g[6];  A1i = f ? g[1] : g[7];
        B1r = f ? g[2] : g[4];  B1i = f ? g[3] : g[5];
    }
    if constexpr (HS == 0) {
        wire_inlane<LY, W, d>(sr, si, A0r, A0i, B0r, B0i, A1r, A1i, B1r, B1i,
                              std::make_integer_sequence<int, 16>{});
    } else if constexpr (d == 0) {
        wire_cross0<LY, W, HS>(sr, si, A0r, A0i, B0r, B0i, A1r, A1i, B1r, B1i,
                               std::make_integer_sequence<int, 16>{});
    } else {
        wire_crossd<LY, W, HS, d>(sr, si, A0r, A0i, B0r, B0i, A1r, A1i, B1r, B1i,
                                  std::make_integer_sequence<int, 16>{});
    }
}

template<int LY>
__device__ __forceinline__ void layer_apply(float* sr, float* si,
        const float* __restrict__ g, int sub) {
    wire_apply<LY, 0>(sr, si, g,      sub);
    wire_apply<LY, 1>(sr, si, g + 8,  sub);
    wire_apply<LY, 2>(sr, si, g + 16, sub);
    wire_apply<LY, 3>(sr, si, g + 24, sub);
    wire_apply<LY, 4>(sr, si, g + 32, sub);
    wire_apply<LY, 5>(sr, si, g + 40, sub);
}

// ---- readout: fold M3 into constexpr signs (l part) + runtime sub flips ----
template<int... Ls>
__device__ __forceinline__ void readout_impl(const float* sr, const float* si, float* q,
                                             std::integer_sequence<int, Ls...>) {
    (([&] {
        constexpr int iv = Minv(3, Ls);
        const float pb = sr[Ls]*sr[Ls] + si[Ls]*si[Ls];
        q[0] += ((iv >> 5) & 1) ? -pb : pb;
        q[1] += ((iv >> 4) & 1) ? -pb : pb;
        q[2] += ((iv >> 3) & 1) ? -pb : pb;
        q[3] += ((iv >> 2) & 1) ? -pb : pb;
        q[4] += ((iv >> 1) & 1) ? -pb : pb;
        q[5] += ( iv       & 1) ? -pb : pb;
    }()), ...);
}

// ---- per-thread gate computation (fallback path only) ----
__device__ __forceinline__ void compute_gates6(const float* __restrict__ th, float* g) {
#pragma unroll
    for (int w = 0; w < NQ; ++w) {
        const float phi = th[w*3+0], theta = th[w*3+1], omega = th[w*3+2];
        float s, c, sa, ca, sb, cb;
        __sincosf(0.5f * theta, &s, &c);
        __sincosf(0.5f * (phi + omega), &sa, &ca);
        __sincosf(0.5f * (phi - omega), &sb, &cb);
        g[w*8+0] =  ca * c;  g[w*8+1] = -sa * c;
        g[w*8+2] = -cb * s;  g[w*8+3] = -sb * s;
        g[w*8+4] =  cb * s;  g[w*8+5] = -sb * s;
        g[w*8+6] =  ca * c;  g[w*8+7] =  sa * c;
    }
}

// ---- setup: gates (18x8) + Gt[j][m] = ln_g[j]*W2[m][j] (64x6) + C1/C2 ----
// ws floats: [0,144) gates, [144,528) Gt (j*6+m), [528,534) C1, [534,540) C2+b2
__global__ void setup_kernel(const float* __restrict__ th_s, const float* __restrict__ th_t,
                             const float* __restrict__ ln_g, const float* __restrict__ ln_b,
                             const float* __restrict__ W2, const float* __restrict__ b2,
                             float* __restrict__ ws) {
    const int t = threadIdx.x;
    if (t < 18) {
        const int l = t / 6, w = t % 6;
        const float* th = (l < 2) ? (th_s + (l * 6 + w) * 3) : (th_t + w * 3);
        const float phi = th[0], theta = th[1], omega = th[2];
        float s, c, sa, ca, sb, cb;
        sincosf(0.5f * theta, &s, &c);
        sincosf(0.5f * (phi + omega), &sa, &ca);
        sincosf(0.5f * (phi - omega), &sb, &cb);
        float* g = ws + t * 8;
        g[0] =  ca * c;  g[1] = -sa * c;
        g[2] = -cb * s;  g[3] = -sb * s;
        g[4] =  cb * s;  g[5] = -sb * s;
        g[6] =  ca * c;  g[7] =  sa * c;
    }
    if (t < 384) {
        const int j = t / 6, m = t % 6;
        ws[144 + t] = ln_g[j] * W2[m * 64 + j];
    }
    if (t < 6) {
        float c1 = 0.f, c2 = 0.f;
        for (int j = 0; j < 64; ++j) {
            c1 += ln_g[j] * W2[t * 64 + j];
            c2 += ln_b[j] * W2[t * 64 + j];
        }
        ws[528 + t] = c1;
        ws[534 + t] = c2 + b2[t];
    }
}

template<bool USE_WS>
__global__ __launch_bounds__(256, 4)   // 128-VGPR budget: allocator fits naturally, no spill
void qmaml_kernel(
    const float* __restrict__ x,  const float* __restrict__ W1, const float* __restrict__ b1,
    const float* __restrict__ ln_g, const float* __restrict__ ln_b,
    const float* __restrict__ W2, const float* __restrict__ b2,
    const float* __restrict__ th_s, const float* __restrict__ th_t,
    const float* __restrict__ Wc, const float* __restrict__ bc,
    const float* __restrict__ ws, float* __restrict__ out, int nrows) {

    // ---- stage W1 into LDS (16 KB): removes L1/L2 latency + contention from
    // the matvec inner loop. 8 blocks x 16 KB = 128 KB <= 160 KB per CU.
    __shared__ float4 wl[1024];
    {
        const float4* wg = (const float4*)W1;
        const int tid = threadIdx.x;
#pragma unroll
        for (int k = 0; k < 4; ++k) wl[tid + (k << 8)] = wg[tid + (k << 8)];
    }
    __syncthreads();

    const int t   = blockIdx.x * 256 + threadIdx.x;
    const int row = t >> 2;
    const int sub = t & 3;             // (wire0,wire1) bits of my 16-amp block
    if (row >= nrows) return;

    // ---- load MY QUARTER of the x row (K-split across the quad) ----
    float4 xv[4];
    const float4* xp = (const float4*)(x + (long)row * 64 + sub * 16);
#pragma unroll
    for (int k = 0; k < 4; ++k) xv[k] = xp[k];

    // ---- fused matvec + relu + LN-stats + folded (g*W2) projection ----
    // Each lane computes a quarter dot; the quad reassembles with two DPP
    // butterflies. All 4 lanes end with bit-identical acc (commutativity),
    // so stats/A stay lockstep-consistent across the quad.
    float A[6]  = {0.f, 0.f, 0.f, 0.f, 0.f, 0.f};
    float C1[6] = {0.f, 0.f, 0.f, 0.f, 0.f, 0.f};
    float C2[6] = {0.f, 0.f, 0.f, 0.f, 0.f, 0.f};
    float s = 0.f, s2 = 0.f;

    const float4* wquarter = &wl[sub * 4];   // lane's 64B quarter base in LDS
#pragma unroll 2
    for (int j = 0; j < 64; ++j) {           // unroll 2: 2x MLP/ILP across iters
        const float4 a4 = wquarter[j * 16 + 0];
        const float4 b4 = wquarter[j * 16 + 1];
        const float4 c4 = wquarter[j * 16 + 2];
        const float4 d4 = wquarter[j * 16 + 3];
        float p0 = 0.f, p1 = 0.f;
        p0 = fmaf(a4.x, xv[0].x, p0); p0 = fmaf(a4.y, xv[0].y, p0);
        p0 = fmaf(a4.z, xv[0].z, p0); p0 = fmaf(a4.w, xv[0].w, p0);
        p1 = fmaf(b4.x, xv[1].x, p1); p1 = fmaf(b4.y, xv[1].y, p1);
        p1 = fmaf(b4.z, xv[1].z, p1); p1 = fmaf(b4.w, xv[1].w, p1);
        p0 = fmaf(c4.x, xv[2].x, p0); p0 = fmaf(c4.y, xv[2].y, p0);
        p0 = fmaf(c4.z, xv[2].z, p0); p0 = fmaf(c4.w, xv[2].w, p0);
        p1 = fmaf(d4.x, xv[3].x, p1); p1 = fmaf(d4.y, xv[3].y, p1);
        p1 = fmaf(d4.z, xv[3].z, p1); p1 = fmaf(d4.w, xv[3].w, p1);
        float p = p0 + p1;
        p += qswap<1>(p);                       // pairwise
        p += qswap<2>(p);                       // full quad: all lanes = total
        const float acc = fmaxf(p + b1[j], 0.f);
        s += acc; s2 += acc * acc;
        if constexpr (USE_WS) {
            const float* Gt = ws + 144 + j * 6;
#pragma unroll
            for (int m = 0; m < 6; ++m) A[m] = fmaf(acc, Gt[m], A[m]);
        } else {
            const float gj = ln_g[j], bj = ln_b[j];
#pragma unroll
            for (int m = 0; m < 6; ++m) {
                const float w2 = W2[m * 64 + j];
                const float gw = gj * w2;
                A[m]  = fmaf(acc, gw, A[m]);
                C1[m] += gw;
                C2[m] = fmaf(bj, w2, C2[m]);
            }
        }
    }

    const float mu  = s  * (1.f / 64.f);
    const float var = s2 * (1.f / 64.f) - mu * mu;
    const float inv = rsqrtf(var + 1e-5f);

    // ---- z = tanh(...), per-wire (cos, sin) ----
    float vc[6], vsn[6];
#pragma unroll
    for (int m = 0; m < 6; ++m) {
        float c1v, c2v;
        if constexpr (USE_WS) { c1v = ws[528 + m]; c2v = ws[534 + m]; }
        else                  { c1v = C1[m];       c2v = C2[m] + b2[m]; }
        const float zp = inv * (A[m] - mu * c1v) + c2v;
        const float e  = __expf(2.f * zp);
        const float z  = 1.f - 2.f / (e + 1.f);
        const float half = 1.57079632679f * z;
        vsn[m] = __sinf(half);
        vc[m]  = __cosf(half);
    }

    float gf[48];
    const float* g0;
    if constexpr (USE_WS) g0 = ws;      // wave-uniform -> SGPR s_loads
    else { compute_gates6(th_s, gf); g0 = gf; }

    // ---- build my 16 amps IN PLACE; per-level folded coefs computed on
    // the fly from (SGPR) gates x vc/vsn -> no gar/gai/gbr/gbi arrays.
    // Backward in-place doubling: write k descending reads k>>1 <= k.
    float sr[16], si[16];
    {
        const int b0 = (sub >> 1) & 1, b1_ = sub & 1;
        // wire0 coefficient, role selected by sub bit1
        const float w0a = b0 ? g0[4] : g0[0];
        const float w0b = b0 ? g0[5] : g0[1];
        const float w0c = b0 ? g0[6] : g0[2];
        const float w0d = b0 ? g0[7] : g0[3];
        const float a0r = w0a * vc[0] + w0c * vsn[0];
        const float a0i = w0b * vc[0] + w0d * vsn[0];
        // wire1 coefficient, role selected by sub bit0
        const float w1a = b1_ ? g0[12] : g0[8];
        const float w1b = b1_ ? g0[13] : g0[9];
        const float w1c = b1_ ? g0[14] : g0[10];
        const float w1d = b1_ ? g0[15] : g0[11];
        const float a1r = w1a * vc[1] + w1c * vsn[1];
        const float a1i = w1b * vc[1] + w1d * vsn[1];
        const float c1r = a0r * a1r - a0i * a1i;
        const float c1i = a0r * a1i + a0i * a1r;
        // wire2 expansion (both roles)
        const float ga2r = g0[16] * vc[2] + g0[18] * vsn[2];
        const float ga2i = g0[17] * vc[2] + g0[19] * vsn[2];
        const float gb2r = g0[20] * vc[2] + g0[22] * vsn[2];
        const float gb2i = g0[21] * vc[2] + g0[23] * vsn[2];
        sr[0] = c1r * ga2r - c1i * ga2i;
        si[0] = c1r * ga2i + c1i * ga2r;
        sr[1] = c1r * gb2r - c1i * gb2i;
        si[1] = c1r * gb2i + c1i * gb2r;
    }
    {   // wire3: 2 -> 4
        const float gaR = g0[24] * vc[3] + g0[26] * vsn[3];
        const float gaI = g0[25] * vc[3] + g0[27] * vsn[3];
        const float gbR = g0[28] * vc[3] + g0[30] * vsn[3];
        const float gbI = g0[29] * vc[3] + g0[31] * vsn[3];
#pragma unroll
        for (int k = 3; k >= 0; --k) {
            const float yr = (k & 1) ? gbR : gaR;
            const float yi = (k & 1) ? gbI : gaI;
            const float hr = sr[k >> 1], hi = si[k >> 1];
            sr[k] = hr * yr - hi * yi;
            si[k] = hr * yi + hi * yr;
        }
    }
    {   // wire4: 4 -> 8
        const float gaR = g0[32] * vc[4] + g0[34] * vsn[4];
        const float gaI = g0[33] * vc[4] + g0[35] * vsn[4];
        const float gbR = g0[36] * vc[4] + g0[38] * vsn[4];
        const float gbI = g0[37] * vc[4] + g0[39] * vsn[4];
#pragma unroll
        for (int k = 7; k >= 0; --k) {
            const float yr = (k & 1) ? gbR : gaR;
            const float yi = (k & 1) ? gbI : gaI;
            const float hr = sr[k >> 1], hi = si[k >> 1];
            sr[k] = hr * yr - hi * yi;
            si[k] = hr * yi + hi * yr;
        }
    }
    {   // wire5: 8 -> 16
        const float gaR = g0[40] * vc[5] + g0[42] * vsn[5];
        const float gaI = g0[41] * vc[5] + g0[43] * vsn[5];
        const float gbR = g0[44] * vc[5] + g0[46] * vsn[5];
        const float gbI = g0[45] * vc[5] + g0[47] * vsn[5];
#pragma unroll
        for (int k = 15; k >= 0; --k) {
            const float yr = (k & 1) ? gbR : gaR;
            const float yi = (k & 1) ? gbI : gaI;
            const float hr = sr[k >> 1], hi = si[k >> 1];
            sr[k] = hr * yr - hi * yi;
            si[k] = hr * yi + hi * yr;
        }
    }

    // ---- layers act through composed maps; NO physical permutations ----
    if constexpr (USE_WS) {
        layer_apply<1>(sr, si, ws + 48, sub);
        layer_apply<2>(sr, si, ws + 96, sub);
    } else {
        compute_gates6(th_s + 18, gf);
        layer_apply<1>(sr, si, gf, sub);
        compute_gates6(th_t, gf);
        layer_apply<2>(sr, si, gf, sub);
    }

    // ---- <Z_w> readout through M3 ----
    float q[6] = {0.f, 0.f, 0.f, 0.f, 0.f, 0.f};
    readout_impl(sr, si, q, std::make_integer_sequence<int, 16>{});

    constexpr int K16 = Minv(3, 16);   // sub bit0 contribution to M3^-1
    constexpr int K32 = Minv(3, 32);   // sub bit1 contribution to M3^-1
    const int s0 = sub & 1, s1 = (sub >> 1) & 1;
#pragma unroll
    for (int w = 0; w < 6; ++w) {
        const int flip = (s0 & ((K16 >> (5 - w)) & 1)) ^ (s1 & ((K32 >> (5 - w)) & 1));
        float tq = flip ? -q[w] : q[w];
        tq += qswap<1>(tq);
        tq += qswap<2>(tq);            // all lanes hold the full quad sum
        q[w] = tq;
    }

    // ---- head: out = q @ Wc^T + bc (split store across the quad) ----
    float o[5];
#pragma unroll
    for (int n = 0; n < 5; ++n) {
        float v = bc[n];
#pragma unroll
        for (int w = 0; w < 6; ++w) v = fmaf(q[w], Wc[n * 6 + w], v);
        o[n] = v;
    }
    float* orow = out + (long)row * 5;
    if (sub == 3) { orow[3] = o[3]; orow[4] = o[4]; }
    else          { orow[sub] = o[sub]; }
}

extern "C" void kernel_launch(void* const* d_in, const int* in_sizes, int n_in,
                              void* d_out, int out_size, void* d_ws, size_t ws_size,
                              hipStream_t stream) {
    const float* x   = (const float*)d_in[0];
    const float* W1  = (const float*)d_in[1];
    const float* b1  = (const float*)d_in[2];
    const float* lng = (const float*)d_in[3];
    const float* lnb = (const float*)d_in[4];
    const float* W2  = (const float*)d_in[5];
    const float* b2  = (const float*)d_in[6];
    const float* ths = (const float*)d_in[7];
    const float* tht = (const float*)d_in[8];
    const float* Wc  = (const float*)d_in[9];
    const float* bc  = (const float*)d_in[10];
    float* out = (float*)d_out;
    float* ws  = (float*)d_ws;

    const int nrows = in_sizes[0] / 64;              // 131072
    const long nthreads = (long)nrows * 4;           // 4 lanes per row
    const int grid = (int)((nthreads + 255) / 256);

    if (ws_size >= 540 * sizeof(float)) {
        setup_kernel<<<1, 384, 0, stream>>>(ths, tht, lng, lnb, W2, b2, ws);
        qmaml_kernel<true><<<grid, 256, 0, stream>>>(x, W1, b1, lng, lnb, W2, b2,
                                                     ths, tht, Wc, bc, ws, out, nrows);
    } else {
        qmaml_kernel<false><<<grid, 256, 0, stream>>>(x, W1, b1, lng, lnb, W2, b2,
                                                      ths, tht, Wc, bc, nullptr, out, nrows);
    }
}

// Round 10
// 149.243 us; speedup vs baseline: 2.7812x; 1.0652x over previous
//
#include <hip/hip_runtime.h>
#include <utility>

#define NQ 6
#define DIM 64

namespace {

// ---- compile-time ring permutation (CNOT ladder), matching _ring_perm ----
constexpr int ring_entry(int r, int i) {
    int idx = i;
    for (int w = NQ - 1; w >= 0; --w) {
        int c = w;
        int t = (w + r) % NQ;
        int cbit = (idx >> (NQ - 1 - c)) & 1;
        idx ^= cbit << (NQ - 1 - t);
    }
    return idx;
}

// Logical->physical composed map after L rings (all rings are GF(2)-linear).
// Rings in order: R1 (after layer0), R2 (after layer1), R1 (after layer2).
constexpr int Mc(int L, int i) {
    if (L == 1) return ring_entry(1, i);
    if (L == 2) return ring_entry(1, ring_entry(2, i));
    if (L == 3) return ring_entry(1, ring_entry(2, ring_entry(1, i)));
    return i;
}

constexpr int Minv(int L, int p) {
    for (int i = 0; i < DIM; ++i) if (Mc(L, i) == p) return i;
    return -1;
}

} // namespace

// ---- 1-instr VALU lane swap (pairs 2r<->2r+1): DPP quad_perm [1,0,3,2] ----
__device__ __forceinline__ float swap1(float v) {
    return __int_as_float(__builtin_amdgcn_mov_dpp(__float_as_int(v), 0xB1, 0xF, 0xF, true));
}

// ===== gate application in the fixed physical frame via composed maps =====
// 2 lanes per row: lane par = t&1 holds physical slots p = par*32 + l, l in [0,32).
// storage: my 32 regs hold physical slots (par, l); logical i = Minv(L, p).

template<int LY, int W, int d, int... Ls>
__device__ __forceinline__ void wire_inlane(float* sr, float* si,
        float A0r, float A0i, float B0r, float B0i,
        float A1r, float A1i, float B1r, float B1i,
        std::integer_sequence<int, Ls...>) {
    (([&] {
        if constexpr (Ls < (Ls ^ d)) {
            constexpr int la = Ls, lb = Ls ^ d;
            constexpr int ra = (Minv(LY, la) >> (5 - W)) & 1;
            constexpr int rb = (Minv(LY, lb) >> (5 - W)) & 1;
            const float cAar = ra ? A1r : A0r, cAai = ra ? A1i : A0i;
            const float cBar = ra ? B1r : B0r, cBai = ra ? B1i : B0i;
            const float cAbr = rb ? A1r : A0r, cAbi = rb ? A1i : A0i;
            const float cBbr = rb ? B1r : B0r, cBbi = rb ? B1i : B0i;
            const float mar = sr[la], mai = si[la];
            const float mbr = sr[lb], mbi = si[lb];
            sr[la] = cAar*mar - cAai*mai + cBar*mbr - cBai*mbi;
            si[la] = cAar*mai + cAai*mar + cBar*mbi + cBai*mbr;
            sr[lb] = cAbr*mbr - cAbi*mbi + cBbr*mar - cBbi*mai;
            si[lb] = cAbr*mbi + cAbi*mbr + cBbr*mai + cBbi*mar;
        }
    }()), ...);
}

template<int LY, int W, int... Ls>
__device__ __forceinline__ void wire_cross0(float* sr, float* si,
        float A0r, float A0i, float B0r, float B0i,
        float A1r, float A1i, float B1r, float B1i,
        std::integer_sequence<int, Ls...>) {
    (([&] {
        constexpr int r = (Minv(LY, Ls) >> (5 - W)) & 1;
        const float cAr = r ? A1r : A0r, cAi = r ? A1i : A0i;
        const float cBr = r ? B1r : B0r, cBi = r ? B1i : B0i;
        const float mr = sr[Ls], mi = si[Ls];
        const float tr = swap1(mr), ti = swap1(mi);   // reads precede writes (lockstep)
        sr[Ls] = cAr*mr - cAi*mi + cBr*tr - cBi*ti;
        si[Ls] = cAr*mi + cAi*mr + cBr*ti + cBi*tr;
    }()), ...);
}

template<int LY, int W, int d, int... Ls>
__device__ __forceinline__ void wire_crossd(float* sr, float* si,
        float A0r, float A0i, float B0r, float B0i,
        float A1r, float A1i, float B1r, float B1i,
        std::integer_sequence<int, Ls...>) {
    (([&] {
        if constexpr (Ls < (Ls ^ d)) {
            constexpr int la = Ls, lb = Ls ^ d;
            constexpr int ra = (Minv(LY, la) >> (5 - W)) & 1;
            constexpr int rb = (Minv(LY, lb) >> (5 - W)) & 1;
            const float cAar = ra ? A1r : A0r, cAai = ra ? A1i : A0i;
            const float cBar = ra ? B1r : B0r, cBai = ra ? B1i : B0i;
            const float cAbr = rb ? A1r : A0r, cAbi = rb ? A1i : A0i;
            const float cBbr = rb ? B1r : B0r, cBbi = rb ? B1i : B0i;
            const float mar = sr[la], mai = si[la];
            const float mbr = sr[lb], mbi = si[lb];
            const float tar = swap1(mbr), tai_ = swap1(mbi);  // partner old [lb]
            const float tbr = swap1(mar), tbi_ = swap1(mai);  // partner old [la]
            sr[la] = cAar*mar - cAai*mai + cBar*tar - cBai*tai_;
            si[la] = cAar*mai + cAai*mar + cBar*tai_ + cBai*tar;
            sr[lb] = cAbr*mbr - cAbi*mbi + cBbr*tbr - cBbi*tbi_;
            si[lb] = cAbr*mbi + cAbi*mbr + cBbr*tbi_ + cBbi*tbr;
        }
    }()), ...);
}

template<int LY, int W>
__device__ __forceinline__ void wire_apply(float* sr, float* si,
        const float* __restrict__ g, bool par) {
    constexpr int D = Mc(LY, 1 << (5 - W));     // physical pair offset (linear map)
    constexpr bool cross = (D >> 5) & 1;
    constexpr int d = D & 31;
    constexpr bool cpar = (Minv(LY, 32) >> (5 - W)) & 1;  // role flips with parity

    // role-hoisted coefficients: slot role = r0(l) ^ (par && cpar)
    float A0r, A0i, B0r, B0i, A1r, A1i, B1r, B1i;
    if constexpr (cpar) {
        A0r = par ? g[6] : g[0];  A0i = par ? g[7] : g[1];
        B0r = par ? g[4] : g[2];  B0i = par ? g[5] : g[3];
        A1r = par ? g[0] : g[6];  A1i = par ? g[1] : g[7];
        B1r = par ? g[2] : g[4];  B1i = par ? g[3] : g[5];
    } else {
        A0r = g[0]; A0i = g[1]; B0r = g[2]; B0i = g[3];
        A1r = g[6]; A1i = g[7]; B1r = g[4]; B1i = g[5];
    }
    if constexpr (!cross) {
        wire_inlane<LY, W, d>(sr, si, A0r, A0i, B0r, B0i, A1r, A1i, B1r, B1i,
                              std::make_integer_sequence<int, 32>{});
    } else if constexpr (d == 0) {
        wire_cross0<LY, W>(sr, si, A0r, A0i, B0r, B0i, A1r, A1i, B1r, B1i,
                           std::make_integer_sequence<int, 32>{});
    } else {
        wire_crossd<LY, W, d>(sr, si, A0r, A0i, B0r, B0i, A1r, A1i, B1r, B1i,
                              std::make_integer_sequence<int, 32>{});
    }
}

template<int LY>
__device__ __forceinline__ void layer_apply(float* sr, float* si,
        const float* __restrict__ g, bool par) {
    wire_apply<LY, 0>(sr, si, g,      par);
    wire_apply<LY, 1>(sr, si, g + 8,  par);
    wire_apply<LY, 2>(sr, si, g + 16, par);
    wire_apply<LY, 3>(sr, si, g + 24, par);
    wire_apply<LY, 4>(sr, si, g + 32, par);
    wire_apply<LY, 5>(sr, si, g + 40, par);
}

// ---- readout: fold full M3 into constexpr signs + one parity flip ----
template<int... Ls>
__device__ __forceinline__ void readout_impl(const float* sr, const float* si, float* q,
                                             std::integer_sequence<int, Ls...>) {
    (([&] {
        constexpr int iv = Minv(3, Ls);
        const float pb = sr[Ls]*sr[Ls] + si[Ls]*si[Ls];
        q[0] += ((iv >> 5) & 1) ? -pb : pb;
        q[1] += ((iv >> 4) & 1) ? -pb : pb;
        q[2] += ((iv >> 3) & 1) ? -pb : pb;
        q[3] += ((iv >> 2) & 1) ? -pb : pb;
        q[4] += ((iv >> 1) & 1) ? -pb : pb;
        q[5] += ( iv       & 1) ? -pb : pb;
    }()), ...);
}

// ---- per-thread gate computation (fallback path only) ----
__device__ __forceinline__ void compute_gates6(const float* __restrict__ th, float* g) {
#pragma unroll
    for (int w = 0; w < NQ; ++w) {
        const float phi = th[w*3+0], theta = th[w*3+1], omega = th[w*3+2];
        float s, c, sa, ca, sb, cb;
        __sincosf(0.5f * theta, &s, &c);
        __sincosf(0.5f * (phi + omega), &sa, &ca);
        __sincosf(0.5f * (phi - omega), &sb, &cb);
        g[w*8+0] =  ca * c;  g[w*8+1] = -sa * c;
        g[w*8+2] = -cb * s;  g[w*8+3] = -sb * s;
        g[w*8+4] =  cb * s;  g[w*8+5] = -sb * s;
        g[w*8+6] =  ca * c;  g[w*8+7] =  sa * c;
    }
}

// ---- setup: gates (18x8) + Gt[j][m] = ln_g[j]*W2[m][j] (64x6) + C1/C2 ----
// ws floats: [0,144) gates, [144,528) Gt (j*6+m), [528,534) C1, [534,540) C2+b2
__global__ void setup_kernel(const float* __restrict__ th_s, const float* __restrict__ th_t,
                             const float* __restrict__ ln_g, const float* __restrict__ ln_b,
                             const float* __restrict__ W2, const float* __restrict__ b2,
                             float* __restrict__ ws) {
    const int t = threadIdx.x;
    if (t < 18) {
        const int l = t / 6, w = t % 6;
        const float* th = (l < 2) ? (th_s + (l * 6 + w) * 3) : (th_t + w * 3);
        const float phi = th[0], theta = th[1], omega = th[2];
        float s, c, sa, ca, sb, cb;
        sincosf(0.5f * theta, &s, &c);
        sincosf(0.5f * (phi + omega), &sa, &ca);
        sincosf(0.5f * (phi - omega), &sb, &cb);
        float* g = ws + t * 8;
        g[0] =  ca * c;  g[1] = -sa * c;
        g[2] = -cb * s;  g[3] = -sb * s;
        g[4] =  cb * s;  g[5] = -sb * s;
        g[6] =  ca * c;  g[7] =  sa * c;
    }
    if (t < 384) {
        const int j = t / 6, m = t % 6;
        ws[144 + t] = ln_g[j] * W2[m * 64 + j];
    }
    if (t < 6) {
        float c1 = 0.f, c2 = 0.f;
        for (int j = 0; j < 64; ++j) {
            c1 += ln_g[j] * W2[t * 64 + j];
            c2 += ln_b[j] * W2[t * 64 + j];
        }
        ws[528 + t] = c1;
        ws[534 + t] = c2 + b2[t];
    }
}

template<bool USE_WS>
__global__ __launch_bounds__(256, 4)   // 128-VGPR budget: allocator fits naturally, no spill
void qmaml_kernel(
    const float* __restrict__ x,  const float* __restrict__ W1, const float* __restrict__ b1,
    const float* __restrict__ ln_g, const float* __restrict__ ln_b,
    const float* __restrict__ W2, const float* __restrict__ b2,
    const float* __restrict__ th_s, const float* __restrict__ th_t,
    const float* __restrict__ Wc, const float* __restrict__ bc,
    const float* __restrict__ ws, float* __restrict__ out, int nrows) {

    // ---- stage W1 into LDS (16 KB): removes L1/L2 latency + contention from
    // the matvec inner loop.
    __shared__ float4 wl[1024];
    {
        const float4* wg = (const float4*)W1;
        const int tid = threadIdx.x;
#pragma unroll
        for (int k = 0; k < 4; ++k) wl[tid + (k << 8)] = wg[tid + (k << 8)];
    }
    __syncthreads();

    const int t   = blockIdx.x * 256 + threadIdx.x;
    const int row = t >> 1;
    const bool par = t & 1;            // = logical wire-0 bit of my half-state
    if (row >= nrows) return;

    // ---- load MY HALF of the x row (K-split across the lane pair) ----
    float4 xv[8];
    const float4* xp = (const float4*)(x + (long)row * 64 + par * 32);
#pragma unroll
    for (int k = 0; k < 8; ++k) xv[k] = xp[k];

    // ---- fused matvec + relu + LN-stats + folded (g*W2) projection ----
    // Each lane computes a half dot (from LDS-resident W1); the pair
    // reassembles with one DPP swap + add per j -> bit-identical acc.
    float A[6]  = {0.f, 0.f, 0.f, 0.f, 0.f, 0.f};
    float C1[6] = {0.f, 0.f, 0.f, 0.f, 0.f, 0.f};
    float C2[6] = {0.f, 0.f, 0.f, 0.f, 0.f, 0.f};
    float s = 0.f, s2 = 0.f;

    const float4* whalf = &wl[par * 8];       // lane's 128B half base in LDS
#pragma unroll 2
    for (int j = 0; j < 64; ++j) {
        const float4* wr = whalf + j * 16;
        float p0 = 0.f, p1 = 0.f;
#pragma unroll
        for (int k = 0; k < 8; k += 2) {
            const float4 a4 = wr[k];
            const float4 b4 = wr[k + 1];
            p0 = fmaf(a4.x, xv[k].x,     p0);
            p0 = fmaf(a4.y, xv[k].y,     p0);
            p0 = fmaf(a4.z, xv[k].z,     p0);
            p0 = fmaf(a4.w, xv[k].w,     p0);
            p1 = fmaf(b4.x, xv[k + 1].x, p1);
            p1 = fmaf(b4.y, xv[k + 1].y, p1);
            p1 = fmaf(b4.z, xv[k + 1].z, p1);
            p1 = fmaf(b4.w, xv[k + 1].w, p1);
        }
        const float p   = p0 + p1;
        const float tot = p + swap1(p);          // full 64-wide dot, both lanes
        const float acc = fmaxf(tot + b1[j], 0.f);
        s += acc; s2 += acc * acc;
        if constexpr (USE_WS) {
            const float* Gt = ws + 144 + j * 6;
#pragma unroll
            for (int m = 0; m < 6; ++m) A[m] = fmaf(acc, Gt[m], A[m]);
        } else {
            const float gj = ln_g[j], bj = ln_b[j];
#pragma unroll
            for (int m = 0; m < 6; ++m) {
                const float w2 = W2[m * 64 + j];
                const float gw = gj * w2;
                A[m]  = fmaf(acc, gw, A[m]);
                C1[m] += gw;
                C2[m] = fmaf(bj, w2, C2[m]);
            }
        }
    }

    const float mu  = s  * (1.f / 64.f);
    const float var = s2 * (1.f / 64.f) - mu * mu;
    const float inv = rsqrtf(var + 1e-5f);

    // ---- z = tanh(...), per-wire (cos, sin) ----
    float vc[6], vsn[6];
#pragma unroll
    for (int m = 0; m < 6; ++m) {
        float c1v, c2v;
        if constexpr (USE_WS) { c1v = ws[528 + m]; c2v = ws[534 + m]; }
        else                  { c1v = C1[m];       c2v = C2[m] + b2[m]; }
        const float zp = inv * (A[m] - mu * c1v) + c2v;
        const float e  = __expf(2.f * zp);
        const float z  = 1.f - 2.f / (e + 1.f);
        const float half = 1.57079632679f * z;
        vsn[m] = __sinf(half);
        vc[m]  = __cosf(half);
    }

    float gf[48];
    const float* g0;
    if constexpr (USE_WS) g0 = ws;      // wave-uniform -> SGPR s_loads
    else { compute_gates6(th_s, gf); g0 = gf; }

    // ---- build my 32 amps IN PLACE; per-level folded coefs computed on
    // the fly from (SGPR) gates x vc/vsn -> no gar/gai/gbr/gbi arrays.
    // Backward in-place doubling: write k descending reads k>>1 <= k.
    float sr[32], si[32];
    {
        // wire0 coefficient, role selected by par
        const float a0r = par ? (g0[4]*vc[0] + g0[6]*vsn[0]) : (g0[0]*vc[0] + g0[2]*vsn[0]);
        const float a0i = par ? (g0[5]*vc[0] + g0[7]*vsn[0]) : (g0[1]*vc[0] + g0[3]*vsn[0]);
        // wire1 expansion (both roles)
        const float ga1r = g0[8]  * vc[1] + g0[10] * vsn[1];
        const float ga1i = g0[9]  * vc[1] + g0[11] * vsn[1];
        const float gb1r = g0[12] * vc[1] + g0[14] * vsn[1];
        const float gb1i = g0[13] * vc[1] + g0[15] * vsn[1];
        sr[0] = a0r * ga1r - a0i * ga1i;
        si[0] = a0r * ga1i + a0i * ga1r;
        sr[1] = a0r * gb1r - a0i * gb1i;
        si[1] = a0r * gb1i + a0i * gb1r;
    }
    {   // wire2: 2 -> 4
        const float gaR = g0[16] * vc[2] + g0[18] * vsn[2];
        const float gaI = g0[17] * vc[2] + g0[19] * vsn[2];
        const float gbR = g0[20] * vc[2] + g0[22] * vsn[2];
        const float gbI = g0[21] * vc[2] + g0[23] * vsn[2];
#pragma unroll
        for (int k = 3; k >= 0; --k) {
            const float yr = (k & 1) ? gbR : gaR;
            const float yi = (k & 1) ? gbI : gaI;
            const float hr = sr[k >> 1], hi = si[k >> 1];
            sr[k] = hr * yr - hi * yi;
            si[k] = hr * yi + hi * yr;
        }
    }
    {   // wire3: 4 -> 8
        const float gaR = g0[24] * vc[3] + g0[26] * vsn[3];
        const float gaI = g0[25] * vc[3] + g0[27] * vsn[3];
        const float gbR = g0[28] * vc[3] + g0[30] * vsn[3];
        const float gbI = g0[29] * vc[3] + g0[31] * vsn[3];
#pragma unroll
        for (int k = 7; k >= 0; --k) {
            const float yr = (k & 1) ? gbR : gaR;
            const float yi = (k & 1) ? gbI : gaI;
            const float hr = sr[k >> 1], hi = si[k >> 1];
            sr[k] = hr * yr - hi * yi;
            si[k] = hr * yi + hi * yr;
        }
    }
    {   // wire4: 8 -> 16
        const float gaR = g0[32] * vc[4] + g0[34] * vsn[4];
        const float gaI = g0[33] * vc[4] + g0[35] * vsn[4];
        const float gbR = g0[36] * vc[4] + g0[38] * vsn[4];
        const float gbI = g0[37] * vc[4] + g0[39] * vsn[4];
#pragma unroll
        for (int k = 15; k >= 0; --k) {
            const float yr = (k & 1) ? gbR : gaR;
            const float yi = (k & 1) ? gbI : gaI;
            const float hr = sr[k >> 1], hi = si[k >> 1];
            sr[k] = hr * yr - hi * yi;
            si[k] = hr * yi + hi * yr;
        }
    }
    {   // wire5: 16 -> 32
        const float gaR = g0[40] * vc[5] + g0[42] * vsn[5];
        const float gaI = g0[41] * vc[5] + g0[43] * vsn[5];
        const float gbR = g0[44] * vc[5] + g0[46] * vsn[5];
        const float gbI = g0[45] * vc[5] + g0[47] * vsn[5];
#pragma unroll
        for (int k = 31; k >= 0; --k) {
            const float yr = (k & 1) ? gbR : gaR;
            const float yi = (k & 1) ? gbI : gaI;
            const float hr = sr[k >> 1], hi = si[k >> 1];
            sr[k] = hr * yr - hi * yi;
            si[k] = hr * yi + hi * yr;
        }
    }

    // ---- layers act through composed maps; NO physical permutations ----
    if constexpr (USE_WS) {
        layer_apply<1>(sr, si, ws + 48, par);
        layer_apply<2>(sr, si, ws + 96, par);
    } else {
        compute_gates6(th_s + 18, gf);
        layer_apply<1>(sr, si, gf, par);
        compute_gates6(th_t, gf);
        layer_apply<2>(sr, si, gf, par);
    }

    // ---- <Z_w> readout through M3 ----
    float q[6] = {0.f, 0.f, 0.f, 0.f, 0.f, 0.f};
    readout_impl(sr, si, q, std::make_integer_sequence<int, 32>{});

    const float pm = par ? -1.f : 1.f;
    constexpr int invC = Minv(3, 32);   // parity contribution to M3^-1
#pragma unroll
    for (int w = 0; w < 6; ++w) {
        float tq = q[w];
        if ((invC >> (5 - w)) & 1) tq *= pm;
        q[w] = tq + swap1(tq);
    }

    // ---- head: out = q @ Wc^T + bc (split store across the lane pair) ----
    float o[5];
#pragma unroll
    for (int n = 0; n < 5; ++n) {
        float v = bc[n];
#pragma unroll
        for (int w = 0; w < 6; ++w) v = fmaf(q[w], Wc[n * 6 + w], v);
        o[n] = v;
    }
    float* orow = out + (long)row * 5;
    if (!par) { orow[0] = o[0]; orow[1] = o[1]; orow[2] = o[2]; }
    else      { orow[3] = o[3]; orow[4] = o[4]; }
}

extern "C" void kernel_launch(void* const* d_in, const int* in_sizes, int n_in,
                              void* d_out, int out_size, void* d_ws, size_t ws_size,
                              hipStream_t stream) {
    const float* x   = (const float*)d_in[0];
    const float* W1  = (const float*)d_in[1];
    const float* b1  = (const float*)d_in[2];
    const float* lng = (const float*)d_in[3];
    const float* lnb = (const float*)d_in[4];
    const float* W2  = (const float*)d_in[5];
    const float* b2  = (const float*)d_in[6];
    const float* ths = (const float*)d_in[7];
    const float* tht = (const float*)d_in[8];
    const float* Wc  = (const float*)d_in[9];
    const float* bc  = (const float*)d_in[10];
    float* out = (float*)d_out;
    float* ws  = (float*)d_ws;

    const int nrows = in_sizes[0] / 64;              // 131072
    const int nthreads = nrows * 2;                  // 2 lanes per row
    const int grid = (nthreads + 255) / 256;

    if (ws_size >= 540 * sizeof(float)) {
        setup_kernel<<<1, 384, 0, stream>>>(ths, tht, lng, lnb, W2, b2, ws);
        qmaml_kernel<true><<<grid, 256, 0, stream>>>(x, W1, b1, lng, lnb, W2, b2,
                                                     ths, tht, Wc, bc, ws, out, nrows);
    } else {
        qmaml_kernel<false><<<grid, 256, 0, stream>>>(x, W1, b1, lng, lnb, W2, b2,
                                                      ths, tht, Wc, bc, nullptr, out, nrows);
    }
}

// Round 11
// 140.585 us; speedup vs baseline: 2.9525x; 1.0616x over previous
//
#include <hip/hip_runtime.h>
#include <utility>

#define NQ 6
#define DIM 64

typedef float v2f __attribute__((ext_vector_type(2)));

namespace {

// ---- compile-time ring permutation (CNOT ladder), matching _ring_perm ----
constexpr int ring_entry(int r, int i) {
    int idx = i;
    for (int w = NQ - 1; w >= 0; --w) {
        int c = w;
        int t = (w + r) % NQ;
        int cbit = (idx >> (NQ - 1 - c)) & 1;
        idx ^= cbit << (NQ - 1 - t);
    }
    return idx;
}

// Logical->physical composed map after L rings (all rings are GF(2)-linear).
constexpr int Mc(int L, int i) {
    if (L == 1) return ring_entry(1, i);
    if (L == 2) return ring_entry(1, ring_entry(2, i));
    if (L == 3) return ring_entry(1, ring_entry(2, ring_entry(1, i)));
    return i;
}

constexpr int Minv(int L, int p) {
    for (int i = 0; i < DIM; ++i) if (Mc(L, i) == p) return i;
    return -1;
}

} // namespace

// ---- 1-instr VALU lane swap (pairs 2r<->2r+1): DPP quad_perm [1,0,3,2] ----
__device__ __forceinline__ float swap1(float v) {
    return __int_as_float(__builtin_amdgcn_mov_dpp(__float_as_int(v), 0xB1, 0xF, 0xF, true));
}
__device__ __forceinline__ v2f swap1v(v2f v) {
    v2f r; r.x = swap1(v.x); r.y = swap1(v.y); return r;
}
// (-v.y, v.x): the i* twiddle -- folds into VOP3P op_sel/neg on pk_fma
__device__ __forceinline__ v2f nsw(v2f v) {
    v2f r; r.x = -v.y; r.y = v.x; return r;
}

// ===== gate application in the fixed physical frame via composed maps =====
// 2 lanes per row: lane par = t&1 holds physical slots p = par*32 + l, l in [0,32).
// state: v2f sv[l] = (re, im) of slot l. logical i = Minv(L, p).

template<int LY, int W, int d, int... Ls>
__device__ __forceinline__ void wire_inlane(v2f* sv,
        float A0r, float A0i, float B0r, float B0i,
        float A1r, float A1i, float B1r, float B1i,
        std::integer_sequence<int, Ls...>) {
    (([&] {
        if constexpr (Ls < (Ls ^ d)) {
            constexpr int la = Ls, lb = Ls ^ d;
            constexpr int ra = (Minv(LY, la) >> (5 - W)) & 1;
            constexpr int rb = (Minv(LY, lb) >> (5 - W)) & 1;
            const float cAar = ra ? A1r : A0r, cAai = ra ? A1i : A0i;
            const float cBar = ra ? B1r : B0r, cBai = ra ? B1i : B0i;
            const float cAbr = rb ? A1r : A0r, cAbi = rb ? A1i : A0i;
            const float cBbr = rb ? B1r : B0r, cBbi = rb ? B1i : B0i;
            const v2f ma = sv[la], mb = sv[lb];
            const v2f na = nsw(ma), nb = nsw(mb);
            sv[la] = cAar*ma + cAai*na + cBar*mb + cBai*nb;
            sv[lb] = cAbr*mb + cAbi*nb + cBbr*ma + cBbi*na;
        }
    }()), ...);
}

template<int LY, int W, int... Ls>
__device__ __forceinline__ void wire_cross0(v2f* sv,
        float A0r, float A0i, float B0r, float B0i,
        float A1r, float A1i, float B1r, float B1i,
        std::integer_sequence<int, Ls...>) {
    (([&] {
        constexpr int r = (Minv(LY, Ls) >> (5 - W)) & 1;
        const float cAr = r ? A1r : A0r, cAi = r ? A1i : A0i;
        const float cBr = r ? B1r : B0r, cBi = r ? B1i : B0i;
        const v2f m = sv[Ls];
        const v2f t = swap1v(m);          // partner lane, same slot (old value)
        sv[Ls] = cAr*m + cAi*nsw(m) + cBr*t + cBi*nsw(t);
    }()), ...);
}

template<int LY, int W, int d, int... Ls>
__device__ __forceinline__ void wire_crossd(v2f* sv,
        float A0r, float A0i, float B0r, float B0i,
        float A1r, float A1i, float B1r, float B1i,
        std::integer_sequence<int, Ls...>) {
    (([&] {
        if constexpr (Ls < (Ls ^ d)) {
            constexpr int la = Ls, lb = Ls ^ d;
            constexpr int ra = (Minv(LY, la) >> (5 - W)) & 1;
            constexpr int rb = (Minv(LY, lb) >> (5 - W)) & 1;
            const float cAar = ra ? A1r : A0r, cAai = ra ? A1i : A0i;
            const float cBar = ra ? B1r : B0r, cBai = ra ? B1i : B0i;
            const float cAbr = rb ? A1r : A0r, cAbi = rb ? A1i : A0i;
            const float cBbr = rb ? B1r : B0r, cBbi = rb ? B1i : B0i;
            const v2f ma = sv[la], mb = sv[lb];
            const v2f ta = swap1v(mb);    // partner lane old [lb]
            const v2f tb = swap1v(ma);    // partner lane old [la]
            sv[la] = cAar*ma + cAai*nsw(ma) + cBar*ta + cBai*nsw(ta);
            sv[lb] = cAbr*mb + cAbi*nsw(mb) + cBbr*tb + cBbi*nsw(tb);
        }
    }()), ...);
}

template<int LY, int W>
__device__ __forceinline__ void wire_apply(v2f* sv,
        const float* __restrict__ g, bool par) {
    constexpr int D = Mc(LY, 1 << (5 - W));     // physical pair offset (linear map)
    constexpr bool cross = (D >> 5) & 1;
    constexpr int d = D & 31;
    constexpr bool cpar = (Minv(LY, 32) >> (5 - W)) & 1;  // role flips with parity

    float A0r, A0i, B0r, B0i, A1r, A1i, B1r, B1i;
    if constexpr (cpar) {
        A0r = par ? g[6] : g[0];  A0i = par ? g[7] : g[1];
        B0r = par ? g[4] : g[2];  B0i = par ? g[5] : g[3];
        A1r = par ? g[0] : g[6];  A1i = par ? g[1] : g[7];
        B1r = par ? g[2] : g[4];  B1i = par ? g[3] : g[5];
    } else {
        A0r = g[0]; A0i = g[1]; B0r = g[2]; B0i = g[3];
        A1r = g[6]; A1i = g[7]; B1r = g[4]; B1i = g[5];
    }
    if constexpr (!cross) {
        wire_inlane<LY, W, d>(sv, A0r, A0i, B0r, B0i, A1r, A1i, B1r, B1i,
                              std::make_integer_sequence<int, 32>{});
    } else if constexpr (d == 0) {
        wire_cross0<LY, W>(sv, A0r, A0i, B0r, B0i, A1r, A1i, B1r, B1i,
                           std::make_integer_sequence<int, 32>{});
    } else {
        wire_crossd<LY, W, d>(sv, A0r, A0i, B0r, B0i, A1r, A1i, B1r, B1i,
                              std::make_integer_sequence<int, 32>{});
    }
}

template<int LY>
__device__ __forceinline__ void layer_apply(v2f* sv,
        const float* __restrict__ g, bool par) {
    wire_apply<LY, 0>(sv, g,      par);
    wire_apply<LY, 1>(sv, g + 8,  par);
    wire_apply<LY, 2>(sv, g + 16, par);
    wire_apply<LY, 3>(sv, g + 24, par);
    wire_apply<LY, 4>(sv, g + 32, par);
    wire_apply<LY, 5>(sv, g + 40, par);
}

// ---- readout: fold full M3 into constexpr signs + one parity flip ----
template<int... Ls>
__device__ __forceinline__ void readout_impl(const v2f* sv, float* q,
                                             std::integer_sequence<int, Ls...>) {
    (([&] {
        constexpr int iv = Minv(3, Ls);
        const float pb = fmaf(sv[Ls].x, sv[Ls].x, sv[Ls].y * sv[Ls].y);
        q[0] += ((iv >> 5) & 1) ? -pb : pb;
        q[1] += ((iv >> 4) & 1) ? -pb : pb;
        q[2] += ((iv >> 3) & 1) ? -pb : pb;
        q[3] += ((iv >> 2) & 1) ? -pb : pb;
        q[4] += ((iv >> 1) & 1) ? -pb : pb;
        q[5] += ( iv       & 1) ? -pb : pb;
    }()), ...);
}

// ---- per-thread gate computation (fallback path only) ----
__device__ __forceinline__ void compute_gates6(const float* __restrict__ th, float* g) {
#pragma unroll
    for (int w = 0; w < NQ; ++w) {
        const float phi = th[w*3+0], theta = th[w*3+1], omega = th[w*3+2];
        float s, c, sa, ca, sb, cb;
        __sincosf(0.5f * theta, &s, &c);
        __sincosf(0.5f * (phi + omega), &sa, &ca);
        __sincosf(0.5f * (phi - omega), &sb, &cb);
        g[w*8+0] =  ca * c;  g[w*8+1] = -sa * c;
        g[w*8+2] = -cb * s;  g[w*8+3] = -sb * s;
        g[w*8+4] =  cb * s;  g[w*8+5] = -sb * s;
        g[w*8+6] =  ca * c;  g[w*8+7] =  sa * c;
    }
}

// ---- setup: gates (18x8) + Gt[j][m] = ln_g[j]*W2[m][j] (64x6) + C1/C2 ----
// ws floats: [0,144) gates, [144,528) Gt (j*6+m), [528,534) C1, [534,540) C2+b2
__global__ void setup_kernel(const float* __restrict__ th_s, const float* __restrict__ th_t,
                             const float* __restrict__ ln_g, const float* __restrict__ ln_b,
                             const float* __restrict__ W2, const float* __restrict__ b2,
                             float* __restrict__ ws) {
    const int t = threadIdx.x;
    if (t < 18) {
        const int l = t / 6, w = t % 6;
        const float* th = (l < 2) ? (th_s + (l * 6 + w) * 3) : (th_t + w * 3);
        const float phi = th[0], theta = th[1], omega = th[2];
        float s, c, sa, ca, sb, cb;
        sincosf(0.5f * theta, &s, &c);
        sincosf(0.5f * (phi + omega), &sa, &ca);
        sincosf(0.5f * (phi - omega), &sb, &cb);
        float* g = ws + t * 8;
        g[0] =  ca * c;  g[1] = -sa * c;
        g[2] = -cb * s;  g[3] = -sb * s;
        g[4] =  cb * s;  g[5] = -sb * s;
        g[6] =  ca * c;  g[7] =  sa * c;
    }
    if (t < 384) {
        const int j = t / 6, m = t % 6;
        ws[144 + t] = ln_g[j] * W2[m * 64 + j];
    }
    if (t < 6) {
        float c1 = 0.f, c2 = 0.f;
        for (int j = 0; j < 64; ++j) {
            c1 += ln_g[j] * W2[t * 64 + j];
            c2 += ln_b[j] * W2[t * 64 + j];
        }
        ws[528 + t] = c1;
        ws[534 + t] = c2 + b2[t];
    }
}

template<bool USE_WS>
__global__ __launch_bounds__(256, 4)   // 128-VGPR budget: allocator fits naturally, no spill
void qmaml_kernel(
    const float* __restrict__ x,  const float* __restrict__ W1, const float* __restrict__ b1,
    const float* __restrict__ ln_g, const float* __restrict__ ln_b,
    const float* __restrict__ W2, const float* __restrict__ b2,
    const float* __restrict__ th_s, const float* __restrict__ th_t,
    const float* __restrict__ Wc, const float* __restrict__ bc,
    const float* __restrict__ ws, float* __restrict__ out, int nrows) {

    // ---- stage W1 into LDS (16 KB) ----
    __shared__ float4 wl[1024];
    {
        const float4* wg = (const float4*)W1;
        const int tid = threadIdx.x;
#pragma unroll
        for (int k = 0; k < 4; ++k) wl[tid + (k << 8)] = wg[tid + (k << 8)];
    }
    __syncthreads();

    const int t   = blockIdx.x * 256 + threadIdx.x;
    const int row = t >> 1;
    const bool par = t & 1;            // = logical wire-0 bit of my half-state
    if (row >= nrows) return;

    // ---- load MY HALF of the x row; re-pack as v2f pairs for pk_fma ----
    float4 xv[8];
    const float4* xp = (const float4*)(x + (long)row * 64 + par * 32);
#pragma unroll
    for (int k = 0; k < 8; ++k) xv[k] = xp[k];
    v2f xl[16];
#pragma unroll
    for (int k = 0; k < 8; ++k) {
        xl[2*k].x   = xv[k].x; xl[2*k].y   = xv[k].y;
        xl[2*k+1].x = xv[k].z; xl[2*k+1].y = xv[k].w;
    }

    // ---- fused matvec + relu + LN-stats + folded (g*W2) projection ----
    // packed dot: 16 v_pk_fma_f32 per j (2 K-elems/instr).
    v2f A2[3]; A2[0] = 0.f; A2[1] = 0.f; A2[2] = 0.f;
    float A[6]  = {0.f, 0.f, 0.f, 0.f, 0.f, 0.f};
    float C1[6] = {0.f, 0.f, 0.f, 0.f, 0.f, 0.f};
    float C2[6] = {0.f, 0.f, 0.f, 0.f, 0.f, 0.f};
    float s = 0.f, s2 = 0.f;

    const float4* whalf = &wl[par * 8];       // lane's 128B half base in LDS
#pragma unroll 2
    for (int j = 0; j < 64; ++j) {
        const float4* wr = whalf + j * 16;
        v2f pa; pa = 0.f;
        v2f pb; pb = 0.f;
#pragma unroll
        for (int k = 0; k < 8; k += 2) {
            const float4 a4 = wr[k];
            const float4 b4 = wr[k + 1];
            v2f w0; w0.x = a4.x; w0.y = a4.y;
            v2f w1; w1.x = a4.z; w1.y = a4.w;
            v2f w2v; w2v.x = b4.x; w2v.y = b4.y;
            v2f w3; w3.x = b4.z; w3.y = b4.w;
            pa = w0  * xl[2*k]     + pa;
            pb = w1  * xl[2*k + 1] + pb;
            pa = w2v * xl[2*k + 2] + pa;
            pb = w3  * xl[2*k + 3] + pb;
        }
        const v2f pv = pa + pb;
        const float p   = pv.x + pv.y;
        const float tot = p + swap1(p);          // full 64-wide dot, both lanes
        const float acc = fmaxf(tot + b1[j], 0.f);
        s += acc; s2 = fmaf(acc, acc, s2);
        if constexpr (USE_WS) {
            const v2f* Gt2 = (const v2f*)(ws + 144 + j * 6);   // 6 floats, 8B-aligned
            A2[0] = acc * Gt2[0] + A2[0];
            A2[1] = acc * Gt2[1] + A2[1];
            A2[2] = acc * Gt2[2] + A2[2];
        } else {
            const float gj = ln_g[j], bj = ln_b[j];
#pragma unroll
            for (int m = 0; m < 6; ++m) {
                const float w2 = W2[m * 64 + j];
                const float gw = gj * w2;
                A[m]  = fmaf(acc, gw, A[m]);
                C1[m] += gw;
                C2[m] = fmaf(bj, w2, C2[m]);
            }
        }
    }
    if constexpr (USE_WS) {
        A[0] = A2[0].x; A[1] = A2[0].y; A[2] = A2[1].x;
        A[3] = A2[1].y; A[4] = A2[2].x; A[5] = A2[2].y;
    }

    const float mu  = s  * (1.f / 64.f);
    const float var = s2 * (1.f / 64.f) - mu * mu;
    const float inv = rsqrtf(var + 1e-5f);

    // ---- z = tanh(...), per-wire (cos, sin) ----
    float vc[6], vsn[6];
#pragma unroll
    for (int m = 0; m < 6; ++m) {
        float c1v, c2v;
        if constexpr (USE_WS) { c1v = ws[528 + m]; c2v = ws[534 + m]; }
        else                  { c1v = C1[m];       c2v = C2[m] + b2[m]; }
        const float zp = inv * (A[m] - mu * c1v) + c2v;
        const float e  = __expf(2.f * zp);
        const float z  = 1.f - 2.f / (e + 1.f);
        const float half = 1.57079632679f * z;
        vsn[m] = __sinf(half);
        vc[m]  = __cosf(half);
    }

    float gf[48];
    const float* g0;
    if constexpr (USE_WS) g0 = ws;      // wave-uniform -> SGPR s_loads
    else { compute_gates6(th_s, gf); g0 = gf; }

    // ---- build my 32 amps IN PLACE as packed complex; 2 pk-ops per step ----
    v2f sv[32];
    {
        const float a0r = par ? (g0[4]*vc[0] + g0[6]*vsn[0]) : (g0[0]*vc[0] + g0[2]*vsn[0]);
        const float a0i = par ? (g0[5]*vc[0] + g0[7]*vsn[0]) : (g0[1]*vc[0] + g0[3]*vsn[0]);
        v2f ga1; ga1.x = g0[8]  * vc[1] + g0[10] * vsn[1];
                 ga1.y = g0[9]  * vc[1] + g0[11] * vsn[1];
        v2f gb1; gb1.x = g0[12] * vc[1] + g0[14] * vsn[1];
                 gb1.y = g0[13] * vc[1] + g0[15] * vsn[1];
        sv[0] = a0r * ga1 + a0i * nsw(ga1);
        sv[1] = a0r * gb1 + a0i * nsw(gb1);
    }
    {   // wire2: 2 -> 4
        v2f ya; ya.x = g0[16]*vc[2] + g0[18]*vsn[2]; ya.y = g0[17]*vc[2] + g0[19]*vsn[2];
        v2f yb; yb.x = g0[20]*vc[2] + g0[22]*vsn[2]; yb.y = g0[21]*vc[2] + g0[23]*vsn[2];
        const v2f nya = nsw(ya), nyb = nsw(yb);
#pragma unroll
        for (int k = 3; k >= 0; --k) {
            const v2f h = sv[k >> 1];
            const v2f y  = (k & 1) ? yb  : ya;
            const v2f ny = (k & 1) ? nyb : nya;
            sv[k] = h.x * y + h.y * ny;
        }
    }
    {   // wire3: 4 -> 8
        v2f ya; ya.x = g0[24]*vc[3] + g0[26]*vsn[3]; ya.y = g0[25]*vc[3] + g0[27]*vsn[3];
        v2f yb; yb.x = g0[28]*vc[3] + g0[30]*vsn[3]; yb.y = g0[29]*vc[3] + g0[31]*vsn[3];
        const v2f nya = nsw(ya), nyb = nsw(yb);
#pragma unroll
        for (int k = 7; k >= 0; --k) {
            const v2f h = sv[k >> 1];
            const v2f y  = (k & 1) ? yb  : ya;
            const v2f ny = (k & 1) ? nyb : nya;
            sv[k] = h.x * y + h.y * ny;
        }
    }
    {   // wire4: 8 -> 16
        v2f ya; ya.x = g0[32]*vc[4] + g0[34]*vsn[4]; ya.y = g0[33]*vc[4] + g0[35]*vsn[4];
        v2f yb; yb.x = g0[36]*vc[4] + g0[38]*vsn[4]; yb.y = g0[37]*vc[4] + g0[39]*vsn[4];
        const v2f nya = nsw(ya), nyb = nsw(yb);
#pragma unroll
        for (int k = 15; k >= 0; --k) {
            const v2f h = sv[k >> 1];
            const v2f y  = (k & 1) ? yb  : ya;
            const v2f ny = (k & 1) ? nyb : nya;
            sv[k] = h.x * y + h.y * ny;
        }
    }
    {   // wire5: 16 -> 32
        v2f ya; ya.x = g0[40]*vc[5] + g0[42]*vsn[5]; ya.y = g0[41]*vc[5] + g0[43]*vsn[5];
        v2f yb; yb.x = g0[44]*vc[5] + g0[46]*vsn[5]; yb.y = g0[45]*vc[5] + g0[47]*vsn[5];
        const v2f nya = nsw(ya), nyb = nsw(yb);
#pragma unroll
        for (int k = 31; k >= 0; --k) {
            const v2f h = sv[k >> 1];
            const v2f y  = (k & 1) ? yb  : ya;
            const v2f ny = (k & 1) ? nyb : nya;
            sv[k] = h.x * y + h.y * ny;
        }
    }

    // ---- layers act through composed maps; NO physical permutations ----
    if constexpr (USE_WS) {
        layer_apply<1>(sv, ws + 48, par);
        layer_apply<2>(sv, ws + 96, par);
    } else {
        compute_gates6(th_s + 18, gf);
        layer_apply<1>(sv, gf, par);
        compute_gates6(th_t, gf);
        layer_apply<2>(sv, gf, par);
    }

    // ---- <Z_w> readout through M3 ----
    float q[6] = {0.f, 0.f, 0.f, 0.f, 0.f, 0.f};
    readout_impl(sv, q, std::make_integer_sequence<int, 32>{});

    const float pm = par ? -1.f : 1.f;
    constexpr int invC = Minv(3, 32);   // parity contribution to M3^-1
#pragma unroll
    for (int w = 0; w < 6; ++w) {
        float tq = q[w];
        if ((invC >> (5 - w)) & 1) tq *= pm;
        q[w] = tq + swap1(tq);
    }

    // ---- head: out = q @ Wc^T + bc (split store across the lane pair) ----
    float o[5];
#pragma unroll
    for (int n = 0; n < 5; ++n) {
        float v = bc[n];
#pragma unroll
        for (int w = 0; w < 6; ++w) v = fmaf(q[w], Wc[n * 6 + w], v);
        o[n] = v;
    }
    float* orow = out + (long)row * 5;
    if (!par) { orow[0] = o[0]; orow[1] = o[1]; orow[2] = o[2]; }
    else      { orow[3] = o[3]; orow[4] = o[4]; }
}

extern "C" void kernel_launch(void* const* d_in, const int* in_sizes, int n_in,
                              void* d_out, int out_size, void* d_ws, size_t ws_size,
                              hipStream_t stream) {
    const float* x   = (const float*)d_in[0];
    const float* W1  = (const float*)d_in[1];
    const float* b1  = (const float*)d_in[2];
    const float* lng = (const float*)d_in[3];
    const float* lnb = (const float*)d_in[4];
    const float* W2  = (const float*)d_in[5];
    const float* b2  = (const float*)d_in[6];
    const float* ths = (const float*)d_in[7];
    const float* tht = (const float*)d_in[8];
    const float* Wc  = (const float*)d_in[9];
    const float* bc  = (const float*)d_in[10];
    float* out = (float*)d_out;
    float* ws  = (float*)d_ws;

    const int nrows = in_sizes[0] / 64;              // 131072
    const int nthreads = nrows * 2;                  // 2 lanes per row
    const int grid = (nthreads + 255) / 256;

    if (ws_size >= 540 * sizeof(float)) {
        setup_kernel<<<1, 384, 0, stream>>>(ths, tht, lng, lnb, W2, b2, ws);
        qmaml_kernel<true><<<grid, 256, 0, stream>>>(x, W1, b1, lng, lnb, W2, b2,
                                                     ths, tht, Wc, bc, ws, out, nrows);
    } else {
        qmaml_kernel<false><<<grid, 256, 0, stream>>>(x, W1, b1, lng, lnb, W2, b2,
                                                      ths, tht, Wc, bc, nullptr, out, nrows);
    }
}